// Round 2
// baseline (933.509 us; speedup 1.0000x reference)
//
#include <hip/hip_runtime.h>
#include <math.h>

#define Cc 128
#define Hh 128
#define Ww 128
#define Bb 8
#define HW 16384
#define NPIX 131072   // B*H*W
#define NOFF 18

// ---------------- K0: repack offset-conv weights to (c, o, k) contiguous ----------------
__global__ __launch_bounds__(256) void k_repack(const float* __restrict__ w_off, float* __restrict__ wp){
  int i = blockIdx.x*256 + threadIdx.x;
  if (i >= NOFF*Cc*9) return;
  int k = i % 9; int t = i / 9; int o = t % NOFF; int c = t / NOFF;
  wp[i] = w_off[(o*Cc + c)*9 + k];
}

// ---------------- K1: offset conv (Cin=128 -> 18, 3x3, pad 1) ----------------
// block = 64 pixels x 4 input-channel groups; LDS reduction across groups.
__global__ __launch_bounds__(256) void k_offset(const float* __restrict__ x, const float* __restrict__ wp,
                                                const float* __restrict__ b_off, float* __restrict__ off){
  int px = threadIdx.x & 63, g = threadIdx.x >> 6;
  int idx = blockIdx.x*64 + px;
  int b = idx >> 14; int rem = idx & 16383; int h = rem >> 7; int w = rem & 127;

  int ofs[9]; float vm[9];
  #pragma unroll
  for (int t=0;t<9;t++){
    int hh = h + t/3 - 1, ww = w + t%3 - 1;
    bool v = (hh>=0)&&(hh<Hh)&&(ww>=0)&&(ww<Ww);
    ofs[t] = v ? (hh*Ww + ww) : 0;
    vm[t]  = v ? 1.f : 0.f;
  }
  float acc[NOFF];
  #pragma unroll
  for (int o=0;o<NOFF;o++) acc[o] = 0.f;

  const float* xb = x + (size_t)b*Cc*HW;
  for (int ci=0; ci<32; ci++){
    int c = g*32 + ci;
    const float* xc = xb + c*HW;
    float xv[9];
    #pragma unroll
    for (int t=0;t<9;t++) xv[t] = xc[ofs[t]] * vm[t];
    const float* wc = wp + c*(NOFF*9);   // wave-uniform address -> scalar loads
    #pragma unroll
    for (int o=0;o<NOFF;o++){
      float a = acc[o];
      #pragma unroll
      for (int k=0;k<9;k++) a = fmaf(xv[k], wc[o*9+k], a);
      acc[o] = a;
    }
  }

  __shared__ float red[4][64][NOFF];
  #pragma unroll
  for (int o=0;o<NOFF;o++) red[g][px][o] = acc[o];
  __syncthreads();
  for (int o=g; o<NOFF; o+=4){
    float s = red[0][px][o] + red[1][px][o] + red[2][px][o] + red[3][px][o] + b_off[o];
    off[((size_t)b*NOFF + o)*HW + rem] = s;
  }
}

// ---------------- K2: deformable depthwise conv ----------------
// block = 64 pixels x 4 channel-groups (32 ch each); tap-outer, channel-inner.
__global__ __launch_bounds__(256,4) void k_deform(const float* __restrict__ x, const float* __restrict__ off,
                                                  const float* __restrict__ w_dw, float* __restrict__ out){
  int px = threadIdx.x & 63, g = threadIdx.x >> 6;
  int idx = blockIdx.x*64 + px;
  int b = idx >> 14; int rem = idx & 16383; int h = rem >> 7; int w = rem & 127;

  const float* offb = off + (size_t)b*NOFF*HW + rem;
  const float* xb   = x   + ((size_t)b*Cc + g*32)*HW;
  float*       ob   = out + ((size_t)b*Cc + g*32)*HW;

  float acc[32];
  #pragma unroll
  for (int ci=0;ci<32;ci++) acc[ci] = 0.f;

  #pragma unroll 1
  for (int kk=0;kk<9;kk++){
    float oy = offb[(kk*2+0)*HW];
    float ox = offb[(kk*2+1)*HW];
    float py = (float)(h + kk/3 - 1) + oy;
    float px_ = (float)(w + kk%3 - 1) + ox;
    float fy = floorf(py), fx = floorf(px_);
    float ty = py - fy, tx = px_ - fx;
    int y0 = (int)fy, x0 = (int)fx;
    int y1 = y0 + 1,  x1 = x0 + 1;
    bool vy0 = (y0>=0)&&(y0<Hh), vy1 = (y1>=0)&&(y1<Hh);
    bool vx0 = (x0>=0)&&(x0<Ww), vx1 = (x1>=0)&&(x1<Ww);
    int yc0 = min(max(y0,0),Hh-1), yc1 = min(max(y1,0),Hh-1);
    int xc0 = min(max(x0,0),Ww-1), xc1 = min(max(x1,0),Ww-1);
    int io0 = yc0*Ww + xc0, io1 = yc0*Ww + xc1, io2 = yc1*Ww + xc0, io3 = yc1*Ww + xc1;
    float cf0 = (vy0&&vx0) ? (1.f-ty)*(1.f-tx) : 0.f;
    float cf1 = (vy0&&vx1) ? (1.f-ty)*tx       : 0.f;
    float cf2 = (vy1&&vx0) ? ty*(1.f-tx)       : 0.f;
    float cf3 = (vy1&&vx1) ? ty*tx             : 0.f;

    const float* wdk = w_dw + (size_t)g*32*9 + kk;  // wave-uniform -> scalar loads
    #pragma unroll
    for (int ci=0;ci<32;ci++){
      const float* xc = xb + (size_t)ci*HW;
      float s =       cf0 * xc[io0];
      s = fmaf(cf1, xc[io1], s);
      s = fmaf(cf2, xc[io2], s);
      s = fmaf(cf3, xc[io3], s);
      acc[ci] = fmaf(wdk[ci*9], s, acc[ci]);
    }
  }
  #pragma unroll
  for (int ci=0;ci<32;ci++) ob[(size_t)ci*HW + rem] = acc[ci];
}

// ---------------- K2b: per-(channel,batch) partial sums ----------------
__global__ __launch_bounds__(256) void k_stats1(const float* __restrict__ dw, float* __restrict__ ps){
  int c = blockIdx.x >> 3, b = blockIdx.x & 7;
  const float4* p = (const float4*)(dw + ((size_t)b*Cc + c)*HW);
  float s = 0.f, s2 = 0.f;
  for (int i=threadIdx.x; i<HW/4; i+=256){
    float4 v = p[i];
    s += v.x + v.y + v.z + v.w;
    s2 = fmaf(v.x, v.x, s2); s2 = fmaf(v.y, v.y, s2);
    s2 = fmaf(v.z, v.z, s2); s2 = fmaf(v.w, v.w, s2);
  }
  #pragma unroll
  for (int d=32; d>0; d>>=1){ s += __shfl_down(s, d, 64); s2 += __shfl_down(s2, d, 64); }
  __shared__ float ls[4], ls2[4];
  int lane = threadIdx.x & 63, wid = threadIdx.x >> 6;
  if (lane==0){ ls[wid]=s; ls2[wid]=s2; }
  __syncthreads();
  if (threadIdx.x==0){
    float S=0.f, S2=0.f;
    #pragma unroll
    for (int i=0;i<4;i++){ S+=ls[i]; S2+=ls2[i]; }
    ps[c*8+b] = S;
    ps[1024 + c*8+b] = S2;
  }
}

// ---------------- K2c: finalize mean/rstd ----------------
__global__ __launch_bounds__(128) void k_stats2(const float* __restrict__ ps, float* __restrict__ mr){
  int c = threadIdx.x;
  float S=0.f, S2=0.f;
  #pragma unroll
  for (int b=0;b<8;b++){ S += ps[c*8+b]; S2 += ps[1024 + c*8+b]; }
  const float invN = 1.f/(float)(Bb*HW);
  float m = S*invN;
  float var = S2*invN - m*m;
  mr[c]      = m;
  mr[Cc + c] = rsqrtf(var + 1e-5f);
}

// ---------------- K3: in-place BN-apply + SiLU + residual (float4) ----------------
__global__ __launch_bounds__(256) void k_apply(float* __restrict__ out, const float* __restrict__ x,
                                               const float* __restrict__ mr, const float* __restrict__ gamma,
                                               const float* __restrict__ beta){
  int i = blockIdx.x*256 + threadIdx.x;          // float4 index
  int c = (i >> 12) & 127;
  float4 v  = ((const float4*)out)[i];
  float4 xi = ((const float4*)x)[i];
  float m = mr[c], r = mr[Cc+c], g = gamma[c], be = beta[c];
  float* vp = (float*)&v; const float* xp = (const float*)&xi;
  float4 o; float* op = (float*)&o;
  #pragma unroll
  for (int j=0;j<4;j++){
    float t = (vp[j]-m)*r*g + be;
    t = t / (1.f + expf(-t));                    // SiLU
    op[j] = t + xp[j];
  }
  ((float4*)out)[i] = o;
}

extern "C" void kernel_launch(void* const* d_in, const int* in_sizes, int n_in,
                              void* d_out, int out_size, void* d_ws, size_t ws_size,
                              hipStream_t stream) {
  const float* x     = (const float*)d_in[0];
  const float* w_off = (const float*)d_in[1];
  const float* b_off = (const float*)d_in[2];
  const float* w_dw  = (const float*)d_in[3];
  const float* gamma = (const float*)d_in[4];
  const float* beta  = (const float*)d_in[5];
  float* out = (float*)d_out;

  float* wp  = (float*)d_ws;               // 20736 floats (repacked w_off)
  float* off = wp + 32768;                 // B*18*HW floats
  float* mr  = off + (size_t)NOFF*NPIX;    // 256 floats (mean | rstd)
  float* ps  = mr + 256;                   // 2048 floats partial sums

  hipLaunchKernelGGL(k_repack, dim3((NOFF*Cc*9 + 255)/256), dim3(256), 0, stream, w_off, wp);
  hipLaunchKernelGGL(k_offset, dim3(NPIX/64), dim3(256), 0, stream, x, wp, b_off, off);
  hipLaunchKernelGGL(k_deform, dim3(NPIX/64), dim3(256), 0, stream, x, off, w_dw, out);
  hipLaunchKernelGGL(k_stats1, dim3(Cc*Bb),   dim3(256), 0, stream, out, ps);
  hipLaunchKernelGGL(k_stats2, dim3(1),       dim3(128), 0, stream, ps, mr);
  hipLaunchKernelGGL(k_apply,  dim3(NPIX*Cc/4/256), dim3(256), 0, stream, out, x, mr, gamma, beta);
}

// Round 3
// 464.413 us; speedup vs baseline: 2.0101x; 2.0101x over previous
//
#include <hip/hip_runtime.h>
#include <math.h>

#define Cc 128
#define Hh 128
#define Ww 128
#define Bb 8
#define HW 16384
#define NPIX 131072   // B*H*W
#define NOFF 18

// ---------------- K0: repack offset-conv weights to [c][k][o(pad 20)] ----------------
__global__ __launch_bounds__(256) void k_repack(const float* __restrict__ w_off, float* __restrict__ wp2){
  int i = blockIdx.x*256 + threadIdx.x;           // over 128*9*20 = 23040
  if (i >= Cc*9*20) return;
  int o = i % 20; int t = i / 20; int k = t % 9; int c = t / 9;
  wp2[i] = (o < NOFF) ? w_off[(o*Cc + c)*9 + k] : 0.f;
}

// ---------------- K1: offset conv (Cin=128 -> 18, 3x3, pad 1) ----------------
// 512 blocks: [b(8)][rowg(16)][colh(2)][chalf(2)]. Block: 256 thr, each 2 pixels
// (rows gr0,gr0+1 of one column). Weights in LDS [64ch][9k][20o], ds_read_b128 broadcast.
// Writes per-chalf partial sums into d_out (used as scratch; overwritten later by k_deform).
__global__ __launch_bounds__(256) void k_offset(const float* __restrict__ x, const float* __restrict__ wp2,
                                                float* __restrict__ part){
  __shared__ float wlds[64*9*20];                  // 46080 B
  int tid = threadIdx.x;
  int chalf = blockIdx.x & 1;
  int pb    = blockIdx.x >> 1;
  int colh  = pb & 1;
  int rowg  = (pb >> 1) & 15;
  int b     = pb >> 5;

  // cooperative weight load: 11520 floats = 2880 float4
  {
    const float4* src = (const float4*)(wp2 + chalf*11520);
    float4* dst = (float4*)wlds;
    for (int i = tid; i < 2880; i += 256) dst[i] = src[i];
  }
  __syncthreads();

  int lane = tid & 63, wid = tid >> 6;
  int gr0 = rowg*8 + wid*2;
  int col = colh*64 + lane;

  int rb[4]; float rm[4];
  #pragma unroll
  for (int j=0;j<4;j++){
    int gr = gr0 - 1 + j;
    rm[j] = (gr>=0 && gr<Hh) ? 1.f : 0.f;
    rb[j] = min(max(gr,0),Hh-1)*Ww;
  }
  int cx[3]; float cm[3];
  #pragma unroll
  for (int s=0;s<3;s++){
    int cc = col + s - 1;
    cm[s] = (cc>=0 && cc<Ww) ? 1.f : 0.f;
    cx[s] = min(max(cc,0),Ww-1);
  }
  float mk[4][3];
  #pragma unroll
  for (int j=0;j<4;j++)
    #pragma unroll
    for (int s=0;s<3;s++) mk[j][s] = rm[j]*cm[s];

  float acc[NOFF][2];
  #pragma unroll
  for (int o=0;o<NOFF;o++){ acc[o][0]=0.f; acc[o][1]=0.f; }

  const float* xb = x + ((size_t)(b*Cc + chalf*64))*HW;
  for (int ci=0; ci<64; ci++){
    const float* xc = xb + (size_t)ci*HW;
    float xv[4][3];
    #pragma unroll
    for (int j=0;j<4;j++)
      #pragma unroll
      for (int s=0;s<3;s++) xv[j][s] = xc[rb[j] + cx[s]] * mk[j][s];

    #pragma unroll
    for (int k=0;k<9;k++){
      const float* wk = &wlds[(ci*9 + k)*20];
      float4 wa = *(const float4*)(wk);
      float4 wb = *(const float4*)(wk+4);
      float4 wc = *(const float4*)(wk+8);
      float4 wd = *(const float4*)(wk+12);
      float2 we = *(const float2*)(wk+16);
      int ky = k/3, kx = k%3;
      float xa = xv[ky][kx], xbv = xv[ky+1][kx];
      acc[0][0]  = fmaf(xa, wa.x, acc[0][0]);   acc[0][1]  = fmaf(xbv, wa.x, acc[0][1]);
      acc[1][0]  = fmaf(xa, wa.y, acc[1][0]);   acc[1][1]  = fmaf(xbv, wa.y, acc[1][1]);
      acc[2][0]  = fmaf(xa, wa.z, acc[2][0]);   acc[2][1]  = fmaf(xbv, wa.z, acc[2][1]);
      acc[3][0]  = fmaf(xa, wa.w, acc[3][0]);   acc[3][1]  = fmaf(xbv, wa.w, acc[3][1]);
      acc[4][0]  = fmaf(xa, wb.x, acc[4][0]);   acc[4][1]  = fmaf(xbv, wb.x, acc[4][1]);
      acc[5][0]  = fmaf(xa, wb.y, acc[5][0]);   acc[5][1]  = fmaf(xbv, wb.y, acc[5][1]);
      acc[6][0]  = fmaf(xa, wb.z, acc[6][0]);   acc[6][1]  = fmaf(xbv, wb.z, acc[6][1]);
      acc[7][0]  = fmaf(xa, wb.w, acc[7][0]);   acc[7][1]  = fmaf(xbv, wb.w, acc[7][1]);
      acc[8][0]  = fmaf(xa, wc.x, acc[8][0]);   acc[8][1]  = fmaf(xbv, wc.x, acc[8][1]);
      acc[9][0]  = fmaf(xa, wc.y, acc[9][0]);   acc[9][1]  = fmaf(xbv, wc.y, acc[9][1]);
      acc[10][0] = fmaf(xa, wc.z, acc[10][0]);  acc[10][1] = fmaf(xbv, wc.z, acc[10][1]);
      acc[11][0] = fmaf(xa, wc.w, acc[11][0]);  acc[11][1] = fmaf(xbv, wc.w, acc[11][1]);
      acc[12][0] = fmaf(xa, wd.x, acc[12][0]);  acc[12][1] = fmaf(xbv, wd.x, acc[12][1]);
      acc[13][0] = fmaf(xa, wd.y, acc[13][0]);  acc[13][1] = fmaf(xbv, wd.y, acc[13][1]);
      acc[14][0] = fmaf(xa, wd.z, acc[14][0]);  acc[14][1] = fmaf(xbv, wd.z, acc[14][1]);
      acc[15][0] = fmaf(xa, wd.w, acc[15][0]);  acc[15][1] = fmaf(xbv, wd.w, acc[15][1]);
      acc[16][0] = fmaf(xa, we.x, acc[16][0]);  acc[16][1] = fmaf(xbv, we.x, acc[16][1]);
      acc[17][0] = fmaf(xa, we.y, acc[17][0]);  acc[17][1] = fmaf(xbv, we.y, acc[17][1]);
    }
  }

  float* pp = part + ((size_t)(chalf*Bb + b)*NOFF)*HW + gr0*Ww + col;
  #pragma unroll
  for (int o=0;o<NOFF;o++){
    pp[(size_t)o*HW]       = acc[o][0];
    pp[(size_t)o*HW + Ww]  = acc[o][1];
  }
}

// ---------------- K1b: combine partials + bias -> off ----------------
__global__ __launch_bounds__(256) void k_comb(const float* __restrict__ part, const float* __restrict__ b_off,
                                              float* __restrict__ off){
  int f = blockIdx.x*256 + threadIdx.x;           // float4 index over 8*18*HW/4
  int o = (f >> 12) % NOFF;
  float4 a = ((const float4*)part)[f];
  float4 c = ((const float4*)(part + (size_t)Bb*NOFF*HW))[f];
  float bo = b_off[o];
  float4 r; r.x=a.x+c.x+bo; r.y=a.y+c.y+bo; r.z=a.z+c.z+bo; r.w=a.w+c.w+bo;
  ((float4*)off)[f] = r;
}

// ---------------- K2: deformable depthwise conv ----------------
// 4096 blocks: [pixblk(2048)][cg(2)]. Block: 64 px x 4 groups of 16 ch. dw-weights in LDS.
__global__ __launch_bounds__(256) void k_deform(const float* __restrict__ x, const float* __restrict__ off,
                                                const float* __restrict__ w_dw, float* __restrict__ out){
  __shared__ float wl[64*9];
  int tid = threadIdx.x;
  int cg = blockIdx.x & 1;
  int pblk = blockIdx.x >> 1;
  for (int i=tid; i<576; i+=256) wl[i] = w_dw[cg*576 + i];
  __syncthreads();

  int px = tid & 63, g = tid >> 6;
  int idx = pblk*64 + px;
  int b = idx >> 14; int rem = idx & 16383; int h = rem >> 7; int w = rem & 127;

  const float* offb = off + (size_t)b*NOFF*HW + rem;
  int ch0 = cg*64 + g*16;
  const float* xb = x   + ((size_t)b*Cc + ch0)*HW;
  float*       ob = out + ((size_t)b*Cc + ch0)*HW;

  float acc[16];
  #pragma unroll
  for (int ci=0;ci<16;ci++) acc[ci] = 0.f;

  #pragma unroll 1
  for (int kk=0;kk<9;kk++){
    float oy = offb[(kk*2+0)*HW];
    float ox = offb[(kk*2+1)*HW];
    float py = (float)(h + kk/3 - 1) + oy;
    float qx = (float)(w + kk%3 - 1) + ox;
    float fy = floorf(py), fx = floorf(qx);
    float ty = py - fy, tx = qx - fx;
    int y0 = (int)fy, x0 = (int)fx;
    int y1 = y0 + 1,  x1 = x0 + 1;
    bool vy0 = (y0>=0)&&(y0<Hh), vy1 = (y1>=0)&&(y1<Hh);
    bool vx0 = (x0>=0)&&(x0<Ww), vx1 = (x1>=0)&&(x1<Ww);
    int yc0 = min(max(y0,0),Hh-1)*Ww, yc1 = min(max(y1,0),Hh-1)*Ww;
    int xc0 = min(max(x0,0),Ww-1),    xc1 = min(max(x1,0),Ww-1);
    int io0 = yc0 + xc0, io1 = yc0 + xc1, io2 = yc1 + xc0, io3 = yc1 + xc1;
    float cf0 = (vy0&&vx0) ? (1.f-ty)*(1.f-tx) : 0.f;
    float cf1 = (vy0&&vx1) ? (1.f-ty)*tx       : 0.f;
    float cf2 = (vy1&&vx0) ? ty*(1.f-tx)       : 0.f;
    float cf3 = (vy1&&vx1) ? ty*tx             : 0.f;

    const float* wlk = &wl[(g*16)*9 + kk];
    #pragma unroll
    for (int ci=0;ci<16;ci++){
      const float* xc = xb + (size_t)ci*HW;
      float s =       cf0 * xc[io0];
      s = fmaf(cf1, xc[io1], s);
      s = fmaf(cf2, xc[io2], s);
      s = fmaf(cf3, xc[io3], s);
      acc[ci] = fmaf(wlk[ci*9], s, acc[ci]);
    }
  }
  #pragma unroll
  for (int ci=0;ci<16;ci++) ob[(size_t)ci*HW + rem] = acc[ci];
}

// ---------------- K2b: per-(channel,batch) partial sums ----------------
__global__ __launch_bounds__(256) void k_stats1(const float* __restrict__ dw, float* __restrict__ ps){
  int c = blockIdx.x >> 3, b = blockIdx.x & 7;
  const float4* p = (const float4*)(dw + ((size_t)b*Cc + c)*HW);
  float s = 0.f, s2 = 0.f;
  for (int i=threadIdx.x; i<HW/4; i+=256){
    float4 v = p[i];
    s += v.x + v.y + v.z + v.w;
    s2 = fmaf(v.x, v.x, s2); s2 = fmaf(v.y, v.y, s2);
    s2 = fmaf(v.z, v.z, s2); s2 = fmaf(v.w, v.w, s2);
  }
  #pragma unroll
  for (int d=32; d>0; d>>=1){ s += __shfl_down(s, d, 64); s2 += __shfl_down(s2, d, 64); }
  __shared__ float ls[4], ls2[4];
  int lane = threadIdx.x & 63, wid = threadIdx.x >> 6;
  if (lane==0){ ls[wid]=s; ls2[wid]=s2; }
  __syncthreads();
  if (threadIdx.x==0){
    float S=0.f, S2=0.f;
    #pragma unroll
    for (int i=0;i<4;i++){ S+=ls[i]; S2+=ls2[i]; }
    ps[c*8+b] = S;
    ps[1024 + c*8+b] = S2;
  }
}

// ---------------- K2c: finalize mean/rstd ----------------
__global__ __launch_bounds__(128) void k_stats2(const float* __restrict__ ps, float* __restrict__ mr){
  int c = threadIdx.x;
  float S=0.f, S2=0.f;
  #pragma unroll
  for (int b=0;b<8;b++){ S += ps[c*8+b]; S2 += ps[1024 + c*8+b]; }
  const float invN = 1.f/(float)(Bb*HW);
  float m = S*invN;
  float var = S2*invN - m*m;
  mr[c]      = m;
  mr[Cc + c] = rsqrtf(var + 1e-5f);
}

// ---------------- K3: in-place BN-apply + SiLU + residual (float4) ----------------
__global__ __launch_bounds__(256) void k_apply(float* __restrict__ out, const float* __restrict__ x,
                                               const float* __restrict__ mr, const float* __restrict__ gamma,
                                               const float* __restrict__ beta){
  int i = blockIdx.x*256 + threadIdx.x;          // float4 index
  int c = (i >> 12) & 127;
  float4 v  = ((const float4*)out)[i];
  float4 xi = ((const float4*)x)[i];
  float m = mr[c], r = mr[Cc+c], g = gamma[c], be = beta[c];
  float* vp = (float*)&v; const float* xp = (const float*)&xi;
  float4 o; float* op = (float*)&o;
  #pragma unroll
  for (int j=0;j<4;j++){
    float t = (vp[j]-m)*r*g + be;
    t = t / (1.f + expf(-t));                    // SiLU
    op[j] = t + xp[j];
  }
  ((float4*)out)[i] = o;
}

extern "C" void kernel_launch(void* const* d_in, const int* in_sizes, int n_in,
                              void* d_out, int out_size, void* d_ws, size_t ws_size,
                              hipStream_t stream) {
  const float* x     = (const float*)d_in[0];
  const float* w_off = (const float*)d_in[1];
  const float* b_off = (const float*)d_in[2];
  const float* w_dw  = (const float*)d_in[3];
  const float* gamma = (const float*)d_in[4];
  const float* beta  = (const float*)d_in[5];
  float* out = (float*)d_out;

  float* wp2 = (float*)d_ws;               // 23040 floats (repacked w_off, [c][k][o20])
  float* off = wp2 + 23040;                // 8*18*HW floats
  float* mr  = off + (size_t)Bb*NOFF*HW;   // 256 floats
  float* ps  = mr + 256;                   // 2048 floats

  // d_out doubles as scratch for k_offset partials (2 x 8*18*HW floats = 18.9 MB < 67 MB)
  hipLaunchKernelGGL(k_repack, dim3((Cc*9*20 + 255)/256), dim3(256), 0, stream, w_off, wp2);
  hipLaunchKernelGGL(k_offset, dim3(512),  dim3(256), 0, stream, x, wp2, out);
  hipLaunchKernelGGL(k_comb,   dim3(Bb*NOFF*HW/4/256), dim3(256), 0, stream, out, b_off, off);
  hipLaunchKernelGGL(k_deform, dim3(4096), dim3(256), 0, stream, x, off, w_dw, out);
  hipLaunchKernelGGL(k_stats1, dim3(Cc*Bb), dim3(256), 0, stream, out, ps);
  hipLaunchKernelGGL(k_stats2, dim3(1),     dim3(128), 0, stream, ps, mr);
  hipLaunchKernelGGL(k_apply,  dim3(NPIX*Cc/4/256), dim3(256), 0, stream, out, x, mr, gamma, beta);
}

// Round 4
// 460.147 us; speedup vs baseline: 2.0287x; 1.0093x over previous
//
#include <hip/hip_runtime.h>
#include <math.h>

#define Cc 128
#define Hh 128
#define Ww 128
#define Bb 8
#define HW 16384
#define NPIX 131072   // B*H*W
#define NOFF 18

// ---------------- K0: repack offset-conv weights to [c][k][o(pad 20)] ----------------
__global__ __launch_bounds__(256) void k_repack(const float* __restrict__ w_off, float* __restrict__ wp2){
  int i = blockIdx.x*256 + threadIdx.x;           // over 128*9*20 = 23040
  if (i >= Cc*9*20) return;
  int o = i % 20; int t = i / 20; int k = t % 9; int c = t / 9;
  wp2[i] = (o < NOFF) ? w_off[(o*Cc + c)*9 + k] : 0.f;
}

// ---------------- K1: offset conv (Cin=128 -> 18, 3x3, pad 1) ----------------
// 512 blocks: [b(8)][rowg(16)][colh(2)][chalf(2)]. Block: 256 thr, each 2 pixels.
// Weights in LDS [64ch][9k][20o], ds_read_b128 broadcast. Partials into d_out (scratch).
__global__ __launch_bounds__(256) void k_offset(const float* __restrict__ x, const float* __restrict__ wp2,
                                                float* __restrict__ part){
  __shared__ float wlds[64*9*20];                  // 46080 B
  int tid = threadIdx.x;
  int chalf = blockIdx.x & 1;
  int pb    = blockIdx.x >> 1;
  int colh  = pb & 1;
  int rowg  = (pb >> 1) & 15;
  int b     = pb >> 5;

  {
    const float4* src = (const float4*)(wp2 + chalf*11520);
    float4* dst = (float4*)wlds;
    for (int i = tid; i < 2880; i += 256) dst[i] = src[i];
  }
  __syncthreads();

  int lane = tid & 63, wid = tid >> 6;
  int gr0 = rowg*8 + wid*2;
  int col = colh*64 + lane;

  int rb[4]; float rm[4];
  #pragma unroll
  for (int j=0;j<4;j++){
    int gr = gr0 - 1 + j;
    rm[j] = (gr>=0 && gr<Hh) ? 1.f : 0.f;
    rb[j] = min(max(gr,0),Hh-1)*Ww;
  }
  int cx[3]; float cm[3];
  #pragma unroll
  for (int s=0;s<3;s++){
    int cc = col + s - 1;
    cm[s] = (cc>=0 && cc<Ww) ? 1.f : 0.f;
    cx[s] = min(max(cc,0),Ww-1);
  }
  float mk[4][3];
  #pragma unroll
  for (int j=0;j<4;j++)
    #pragma unroll
    for (int s=0;s<3;s++) mk[j][s] = rm[j]*cm[s];

  float acc[NOFF][2];
  #pragma unroll
  for (int o=0;o<NOFF;o++){ acc[o][0]=0.f; acc[o][1]=0.f; }

  const float* xb = x + ((size_t)(b*Cc + chalf*64))*HW;
  for (int ci=0; ci<64; ci++){
    const float* xc = xb + (size_t)ci*HW;
    float xv[4][3];
    #pragma unroll
    for (int j=0;j<4;j++)
      #pragma unroll
      for (int s=0;s<3;s++) xv[j][s] = xc[rb[j] + cx[s]] * mk[j][s];

    #pragma unroll
    for (int k=0;k<9;k++){
      const float* wk = &wlds[(ci*9 + k)*20];
      float4 wa = *(const float4*)(wk);
      float4 wb = *(const float4*)(wk+4);
      float4 wc = *(const float4*)(wk+8);
      float4 wd = *(const float4*)(wk+12);
      float2 we = *(const float2*)(wk+16);
      int ky = k/3, kx = k%3;
      float xa = xv[ky][kx], xbv = xv[ky+1][kx];
      acc[0][0]  = fmaf(xa, wa.x, acc[0][0]);   acc[0][1]  = fmaf(xbv, wa.x, acc[0][1]);
      acc[1][0]  = fmaf(xa, wa.y, acc[1][0]);   acc[1][1]  = fmaf(xbv, wa.y, acc[1][1]);
      acc[2][0]  = fmaf(xa, wa.z, acc[2][0]);   acc[2][1]  = fmaf(xbv, wa.z, acc[2][1]);
      acc[3][0]  = fmaf(xa, wa.w, acc[3][0]);   acc[3][1]  = fmaf(xbv, wa.w, acc[3][1]);
      acc[4][0]  = fmaf(xa, wb.x, acc[4][0]);   acc[4][1]  = fmaf(xbv, wb.x, acc[4][1]);
      acc[5][0]  = fmaf(xa, wb.y, acc[5][0]);   acc[5][1]  = fmaf(xbv, wb.y, acc[5][1]);
      acc[6][0]  = fmaf(xa, wb.z, acc[6][0]);   acc[6][1]  = fmaf(xbv, wb.z, acc[6][1]);
      acc[7][0]  = fmaf(xa, wb.w, acc[7][0]);   acc[7][1]  = fmaf(xbv, wb.w, acc[7][1]);
      acc[8][0]  = fmaf(xa, wc.x, acc[8][0]);   acc[8][1]  = fmaf(xbv, wc.x, acc[8][1]);
      acc[9][0]  = fmaf(xa, wc.y, acc[9][0]);   acc[9][1]  = fmaf(xbv, wc.y, acc[9][1]);
      acc[10][0] = fmaf(xa, wc.z, acc[10][0]);  acc[10][1] = fmaf(xbv, wc.z, acc[10][1]);
      acc[11][0] = fmaf(xa, wc.w, acc[11][0]);  acc[11][1] = fmaf(xbv, wc.w, acc[11][1]);
      acc[12][0] = fmaf(xa, wd.x, acc[12][0]);  acc[12][1] = fmaf(xbv, wd.x, acc[12][1]);
      acc[13][0] = fmaf(xa, wd.y, acc[13][0]);  acc[13][1] = fmaf(xbv, wd.y, acc[13][1]);
      acc[14][0] = fmaf(xa, wd.z, acc[14][0]);  acc[14][1] = fmaf(xbv, wd.z, acc[14][1]);
      acc[15][0] = fmaf(xa, wd.w, acc[15][0]);  acc[15][1] = fmaf(xbv, wd.w, acc[15][1]);
      acc[16][0] = fmaf(xa, we.x, acc[16][0]);  acc[16][1] = fmaf(xbv, we.x, acc[16][1]);
      acc[17][0] = fmaf(xa, we.y, acc[17][0]);  acc[17][1] = fmaf(xbv, we.y, acc[17][1]);
    }
  }

  float* pp = part + ((size_t)(chalf*Bb + b)*NOFF)*HW + gr0*Ww + col;
  #pragma unroll
  for (int o=0;o<NOFF;o++){
    pp[(size_t)o*HW]       = acc[o][0];
    pp[(size_t)o*HW + Ww]  = acc[o][1];
  }
}

// ---------------- K1b: combine partials + bias -> off ----------------
__global__ __launch_bounds__(256) void k_comb(const float* __restrict__ part, const float* __restrict__ b_off,
                                              float* __restrict__ off){
  int f = blockIdx.x*256 + threadIdx.x;           // float4 index over 8*18*HW/4
  int o = (f >> 12) % NOFF;
  float4 a = ((const float4*)part)[f];
  float4 c = ((const float4*)(part + (size_t)Bb*NOFF*HW))[f];
  float bo = b_off[o];
  float4 r; r.x=a.x+c.x+bo; r.y=a.y+c.y+bo; r.z=a.z+c.z+bo; r.w=a.w+c.w+bo;
  ((float4*)off)[f] = r;
}

// ---------------- K2: deformable depthwise conv ----------------
// 4096 blocks: [pixblk(2048)][cg(2)]. Block: 64 px x 4 groups of 16 ch.
// All offsets hoisted; 36 (byte-offset, coef) precomputed; channel loop pipelined;
// depthwise weights via readfirstlane-uniform scalar loads.
__global__ __launch_bounds__(256) void k_deform(const float* __restrict__ x, const float* __restrict__ off,
                                                const float* __restrict__ w_dw, float* __restrict__ out){
  int tid = threadIdx.x;
  int cg = blockIdx.x & 1;
  int pblk = blockIdx.x >> 1;
  int px = tid & 63, g = tid >> 6;
  int gu = __builtin_amdgcn_readfirstlane(g);
  int idx = pblk*64 + px;
  int b = idx >> 14; int rem = idx & 16383; int h = rem >> 7; int w = rem & 127;

  const float* offb = off + (size_t)b*NOFF*HW + rem;
  int ch0 = cg*64 + gu*16;
  const float* xb  = x   + ((size_t)b*Cc + ch0)*HW;
  float*       ob  = out + ((size_t)b*Cc + ch0)*HW;
  const float* wdw = w_dw + ch0*9;     // wave-uniform base -> scalar loads

  float oy[9], ox[9];
  #pragma unroll
  for (int kk=0;kk<9;kk++){
    oy[kk] = offb[(size_t)(2*kk)*HW];
    ox[kk] = offb[(size_t)(2*kk+1)*HW];
  }

  int iob[9][4]; float cf[9][4];
  #pragma unroll
  for (int kk=0;kk<9;kk++){
    float py = (float)(h + kk/3 - 1) + oy[kk];
    float qx = (float)(w + kk%3 - 1) + ox[kk];
    float fy = floorf(py), fx = floorf(qx);
    float ty = py - fy, tx = qx - fx;
    int y0 = (int)fy, x0 = (int)fx;
    int y1 = y0 + 1,  x1 = x0 + 1;
    bool vy0 = (y0>=0)&&(y0<Hh), vy1 = (y1>=0)&&(y1<Hh);
    bool vx0 = (x0>=0)&&(x0<Ww), vx1 = (x1>=0)&&(x1<Ww);
    int yc0 = min(max(y0,0),Hh-1)*Ww, yc1 = min(max(y1,0),Hh-1)*Ww;
    int xc0 = min(max(x0,0),Ww-1),    xc1 = min(max(x1,0),Ww-1);
    iob[kk][0] = (yc0 + xc0)*4; iob[kk][1] = (yc0 + xc1)*4;
    iob[kk][2] = (yc1 + xc0)*4; iob[kk][3] = (yc1 + xc1)*4;
    cf[kk][0] = (vy0&&vx0) ? (1.f-ty)*(1.f-tx) : 0.f;
    cf[kk][1] = (vy0&&vx1) ? (1.f-ty)*tx       : 0.f;
    cf[kk][2] = (vy1&&vx0) ? ty*(1.f-tx)       : 0.f;
    cf[kk][3] = (vy1&&vx1) ? ty*tx             : 0.f;
  }

  #pragma unroll 2
  for (int ci=0;ci<16;ci++){
    const char* xc = (const char*)(xb + (size_t)ci*HW);
    float v[9][4];
    #pragma unroll
    for (int kk=0;kk<9;kk++)
      #pragma unroll
      for (int j=0;j<4;j++)
        v[kk][j] = *(const float*)(xc + iob[kk][j]);
    float o = 0.f;
    #pragma unroll
    for (int kk=0;kk<9;kk++){
      float s =       cf[kk][0]*v[kk][0];
      s = fmaf(cf[kk][1], v[kk][1], s);
      s = fmaf(cf[kk][2], v[kk][2], s);
      s = fmaf(cf[kk][3], v[kk][3], s);
      o = fmaf(wdw[ci*9+kk], s, o);
    }
    ob[(size_t)ci*HW + rem] = o;
  }
}

// ---------------- K2b: per-(channel,batch) partial sums ----------------
__global__ __launch_bounds__(256) void k_stats1(const float* __restrict__ dw, float* __restrict__ ps){
  int c = blockIdx.x >> 3, b = blockIdx.x & 7;
  const float4* p = (const float4*)(dw + ((size_t)b*Cc + c)*HW);
  float s = 0.f, s2 = 0.f;
  for (int i=threadIdx.x; i<HW/4; i+=256){
    float4 v = p[i];
    s += v.x + v.y + v.z + v.w;
    s2 = fmaf(v.x, v.x, s2); s2 = fmaf(v.y, v.y, s2);
    s2 = fmaf(v.z, v.z, s2); s2 = fmaf(v.w, v.w, s2);
  }
  #pragma unroll
  for (int d=32; d>0; d>>=1){ s += __shfl_down(s, d, 64); s2 += __shfl_down(s2, d, 64); }
  __shared__ float ls[4], ls2[4];
  int lane = threadIdx.x & 63, wid = threadIdx.x >> 6;
  if (lane==0){ ls[wid]=s; ls2[wid]=s2; }
  __syncthreads();
  if (threadIdx.x==0){
    float S=0.f, S2=0.f;
    #pragma unroll
    for (int i=0;i<4;i++){ S+=ls[i]; S2+=ls2[i]; }
    ps[c*8+b] = S;
    ps[1024 + c*8+b] = S2;
  }
}

// ---------------- K2c: finalize mean/rstd ----------------
__global__ __launch_bounds__(128) void k_stats2(const float* __restrict__ ps, float* __restrict__ mr){
  int c = threadIdx.x;
  float S=0.f, S2=0.f;
  #pragma unroll
  for (int b=0;b<8;b++){ S += ps[c*8+b]; S2 += ps[1024 + c*8+b]; }
  const float invN = 1.f/(float)(Bb*HW);
  float m = S*invN;
  float var = S2*invN - m*m;
  mr[c]      = m;
  mr[Cc + c] = rsqrtf(var + 1e-5f);
}

// ---------------- K3: in-place BN-apply + SiLU + residual (float4) ----------------
__global__ __launch_bounds__(256) void k_apply(float* __restrict__ out, const float* __restrict__ x,
                                               const float* __restrict__ mr, const float* __restrict__ gamma,
                                               const float* __restrict__ beta){
  int i = blockIdx.x*256 + threadIdx.x;          // float4 index
  int c = (i >> 12) & 127;
  float4 v  = ((const float4*)out)[i];
  float4 xi = ((const float4*)x)[i];
  float m = mr[c], r = mr[Cc+c], g = gamma[c], be = beta[c];
  float* vp = (float*)&v; const float* xp = (const float*)&xi;
  float4 o; float* op = (float*)&o;
  #pragma unroll
  for (int j=0;j<4;j++){
    float t = (vp[j]-m)*r*g + be;
    t = t / (1.f + expf(-t));                    // SiLU
    op[j] = t + xp[j];
  }
  ((float4*)out)[i] = o;
}

extern "C" void kernel_launch(void* const* d_in, const int* in_sizes, int n_in,
                              void* d_out, int out_size, void* d_ws, size_t ws_size,
                              hipStream_t stream) {
  const float* x     = (const float*)d_in[0];
  const float* w_off = (const float*)d_in[1];
  const float* b_off = (const float*)d_in[2];
  const float* w_dw  = (const float*)d_in[3];
  const float* gamma = (const float*)d_in[4];
  const float* beta  = (const float*)d_in[5];
  float* out = (float*)d_out;

  float* wp2 = (float*)d_ws;               // 23040 floats (repacked w_off, [c][k][o20])
  float* off = wp2 + 23040;                // 8*18*HW floats
  float* mr  = off + (size_t)Bb*NOFF*HW;   // 256 floats
  float* ps  = mr + 256;                   // 2048 floats

  // d_out doubles as scratch for k_offset partials (2 x 8*18*HW floats = 18.9 MB < 67 MB)
  hipLaunchKernelGGL(k_repack, dim3((Cc*9*20 + 255)/256), dim3(256), 0, stream, w_off, wp2);
  hipLaunchKernelGGL(k_offset, dim3(512),  dim3(256), 0, stream, x, wp2, out);
  hipLaunchKernelGGL(k_comb,   dim3(Bb*NOFF*HW/4/256), dim3(256), 0, stream, out, b_off, off);
  hipLaunchKernelGGL(k_deform, dim3(4096), dim3(256), 0, stream, x, off, w_dw, out);
  hipLaunchKernelGGL(k_stats1, dim3(Cc*Bb), dim3(256), 0, stream, out, ps);
  hipLaunchKernelGGL(k_stats2, dim3(1),     dim3(128), 0, stream, ps, mr);
  hipLaunchKernelGGL(k_apply,  dim3(NPIX*Cc/4/256), dim3(256), 0, stream, out, x, mr, gamma, beta);
}

// Round 5
// 344.462 us; speedup vs baseline: 2.7101x; 1.3358x over previous
//
#include <hip/hip_runtime.h>
#include <math.h>

#define Cc 128
#define Hh 128
#define Ww 128
#define Bb 8
#define HW 16384
#define NPIX 131072   // B*H*W
#define NOFF 18

// ---------------- K0: repack offset-conv weights [c][k][o(pad20)] + w_dw transpose [k][c] ----------------
__global__ __launch_bounds__(256) void k_repack(const float* __restrict__ w_off, const float* __restrict__ w_dw,
                                                float* __restrict__ wp2, float* __restrict__ wdt){
  int i = blockIdx.x*256 + threadIdx.x;
  if (i < Cc*9*20){
    int o = i % 20; int t = i / 20; int k = t % 9; int c = t / 9;
    wp2[i] = (o < NOFF) ? w_off[(o*Cc + c)*9 + k] : 0.f;
  }
  int j = i - Cc*9*20;
  if (j >= 0 && j < 9*Cc){
    int c = j % Cc; int k = j / Cc;
    wdt[j] = w_dw[c*9 + k];
  }
}

// ---------------- K1: offset conv (Cin=128 -> 18, 3x3, pad 1) ----------------
// 512 blocks: [b(8)][rowg(16)][colh(2)][chalf(2)]. Partials into d_out (scratch).
__global__ __launch_bounds__(256) void k_offset(const float* __restrict__ x, const float* __restrict__ wp2,
                                                float* __restrict__ part){
  __shared__ float wlds[64*9*20];
  int tid = threadIdx.x;
  int chalf = blockIdx.x & 1;
  int pb    = blockIdx.x >> 1;
  int colh  = pb & 1;
  int rowg  = (pb >> 1) & 15;
  int b     = pb >> 5;

  {
    const float4* src = (const float4*)(wp2 + chalf*11520);
    float4* dst = (float4*)wlds;
    for (int i = tid; i < 2880; i += 256) dst[i] = src[i];
  }
  __syncthreads();

  int lane = tid & 63, wid = tid >> 6;
  int gr0 = rowg*8 + wid*2;
  int col = colh*64 + lane;

  int rb[4]; float rm[4];
  #pragma unroll
  for (int j=0;j<4;j++){
    int gr = gr0 - 1 + j;
    rm[j] = (gr>=0 && gr<Hh) ? 1.f : 0.f;
    rb[j] = min(max(gr,0),Hh-1)*Ww;
  }
  int cx[3]; float cm[3];
  #pragma unroll
  for (int s=0;s<3;s++){
    int cc = col + s - 1;
    cm[s] = (cc>=0 && cc<Ww) ? 1.f : 0.f;
    cx[s] = min(max(cc,0),Ww-1);
  }
  float mk[4][3];
  #pragma unroll
  for (int j=0;j<4;j++)
    #pragma unroll
    for (int s=0;s<3;s++) mk[j][s] = rm[j]*cm[s];

  float acc[NOFF][2];
  #pragma unroll
  for (int o=0;o<NOFF;o++){ acc[o][0]=0.f; acc[o][1]=0.f; }

  const float* xb = x + ((size_t)(b*Cc + chalf*64))*HW;
  for (int ci=0; ci<64; ci++){
    const float* xc = xb + (size_t)ci*HW;
    float xv[4][3];
    #pragma unroll
    for (int j=0;j<4;j++)
      #pragma unroll
      for (int s=0;s<3;s++) xv[j][s] = xc[rb[j] + cx[s]] * mk[j][s];

    #pragma unroll
    for (int k=0;k<9;k++){
      const float* wk = &wlds[(ci*9 + k)*20];
      float4 wa = *(const float4*)(wk);
      float4 wb = *(const float4*)(wk+4);
      float4 wc = *(const float4*)(wk+8);
      float4 wd = *(const float4*)(wk+12);
      float2 we = *(const float2*)(wk+16);
      int ky = k/3, kx = k%3;
      float xa = xv[ky][kx], xbv = xv[ky+1][kx];
      acc[0][0]  = fmaf(xa, wa.x, acc[0][0]);   acc[0][1]  = fmaf(xbv, wa.x, acc[0][1]);
      acc[1][0]  = fmaf(xa, wa.y, acc[1][0]);   acc[1][1]  = fmaf(xbv, wa.y, acc[1][1]);
      acc[2][0]  = fmaf(xa, wa.z, acc[2][0]);   acc[2][1]  = fmaf(xbv, wa.z, acc[2][1]);
      acc[3][0]  = fmaf(xa, wa.w, acc[3][0]);   acc[3][1]  = fmaf(xbv, wa.w, acc[3][1]);
      acc[4][0]  = fmaf(xa, wb.x, acc[4][0]);   acc[4][1]  = fmaf(xbv, wb.x, acc[4][1]);
      acc[5][0]  = fmaf(xa, wb.y, acc[5][0]);   acc[5][1]  = fmaf(xbv, wb.y, acc[5][1]);
      acc[6][0]  = fmaf(xa, wb.z, acc[6][0]);   acc[6][1]  = fmaf(xbv, wb.z, acc[6][1]);
      acc[7][0]  = fmaf(xa, wb.w, acc[7][0]);   acc[7][1]  = fmaf(xbv, wb.w, acc[7][1]);
      acc[8][0]  = fmaf(xa, wc.x, acc[8][0]);   acc[8][1]  = fmaf(xbv, wc.x, acc[8][1]);
      acc[9][0]  = fmaf(xa, wc.y, acc[9][0]);   acc[9][1]  = fmaf(xbv, wc.y, acc[9][1]);
      acc[10][0] = fmaf(xa, wc.z, acc[10][0]);  acc[10][1] = fmaf(xbv, wc.z, acc[10][1]);
      acc[11][0] = fmaf(xa, wc.w, acc[11][0]);  acc[11][1] = fmaf(xbv, wc.w, acc[11][1]);
      acc[12][0] = fmaf(xa, wd.x, acc[12][0]);  acc[12][1] = fmaf(xbv, wd.x, acc[12][1]);
      acc[13][0] = fmaf(xa, wd.y, acc[13][0]);  acc[13][1] = fmaf(xbv, wd.y, acc[13][1]);
      acc[14][0] = fmaf(xa, wd.z, acc[14][0]);  acc[14][1] = fmaf(xbv, wd.z, acc[14][1]);
      acc[15][0] = fmaf(xa, wd.w, acc[15][0]);  acc[15][1] = fmaf(xbv, wd.w, acc[15][1]);
      acc[16][0] = fmaf(xa, we.x, acc[16][0]);  acc[16][1] = fmaf(xbv, we.x, acc[16][1]);
      acc[17][0] = fmaf(xa, we.y, acc[17][0]);  acc[17][1] = fmaf(xbv, we.y, acc[17][1]);
    }
  }

  float* pp = part + ((size_t)(chalf*Bb + b)*NOFF)*HW + gr0*Ww + col;
  #pragma unroll
  for (int o=0;o<NOFF;o++){
    pp[(size_t)o*HW]       = acc[o][0];
    pp[(size_t)o*HW + Ww]  = acc[o][1];
  }
}

// ---------------- K_tx: transpose x NCHW -> NHWC (LDS-tiled) ----------------
__global__ __launch_bounds__(256) void k_tx(const float* __restrict__ x, float* __restrict__ xt){
  __shared__ float t[128][65];
  int tid = threadIdx.x;
  int b   = blockIdx.x >> 8;             // 256 tiles of 64 hw per batch
  int hw0 = (blockIdx.x & 255) << 6;
  int lane = tid & 63, wg = tid >> 6;
  const float* xb = x + (size_t)b*Cc*HW;
  #pragma unroll
  for (int k=0;k<32;k++){
    int c = wg + k*4;
    t[c][lane] = xb[(size_t)c*HW + hw0 + lane];
  }
  __syncthreads();
  float* ob = xt + ((size_t)b*HW + hw0)*Cc;
  int c2 = tid & 127, half = tid >> 7;
  #pragma unroll
  for (int k=0;k<32;k++){
    int hwl = half + k*2;
    ob[(size_t)hwl*Cc + c2] = t[c2][hwl];
  }
}

// ---------------- K1b (big): combine partials + bias -> per-pixel records [px][20] ----------------
__global__ __launch_bounds__(256) void k_comb_nx(const float* __restrict__ part, const float* __restrict__ b_off,
                                                 float* __restrict__ offx){
  int px = blockIdx.x*256 + threadIdx.x;      // 131072
  int b = px >> 14, hw = px & 16383;
  float v[20];
  #pragma unroll
  for (int o=0;o<NOFF;o++){
    float a = part[((size_t)(b)*NOFF + o)*HW + hw];
    float c = part[((size_t)(Bb + b)*NOFF + o)*HW + hw];
    v[o] = a + c + b_off[o];
  }
  v[18] = 0.f; v[19] = 0.f;
  float* dst = offx + (size_t)px*20;
  #pragma unroll
  for (int q=0;q<5;q++)
    *(float4*)(dst + q*4) = *(float4*)(v + q*4);
}

// ---------------- K2 (big): deformable depthwise, NHWC reads, NCHW writes via LDS pivot ----------------
// wave = 1 pixel; lane covers channels {2*lane, 2*lane+1}; block = 4 waves = 4 pixels.
__global__ __launch_bounds__(256) void k_deform_nx(const float* __restrict__ xt, const float* __restrict__ offx,
                                                   const float* __restrict__ wdt, float* __restrict__ out){
  __shared__ float pivot[4][128];
  int tid = threadIdx.x;
  int lane = tid & 63, wid = tid >> 6;
  int px0 = blockIdx.x << 2;
  int pu  = __builtin_amdgcn_readfirstlane(px0 + wid);
  int bu  = pu >> 14;
  int rem = pu & 16383;
  int h = rem >> 7, w = rem & 127;

  const float4* op = (const float4*)(offx + (size_t)pu*20);   // wave-uniform
  float4 a0 = op[0], a1 = op[1], a2 = op[2], a3 = op[3];
  float4 a4 = op[4];

  float2 wk[9];
  #pragma unroll
  for (int k=0;k<9;k++) wk[k] = *(const float2*)(wdt + k*Cc + lane*2);

  const float* xb = xt + (size_t)bu*HW*Cc;
  float acc0 = 0.f, acc1 = 0.f;

  float oys[9] = {a0.x,a0.z,a1.x,a1.z,a2.x,a2.z,a3.x,a3.z,a4.x};
  float oxs[9] = {a0.y,a0.w,a1.y,a1.w,a2.y,a2.w,a3.y,a3.w,a4.y};

  #pragma unroll
  for (int kk=0;kk<9;kk++){
    float py = (float)(h + kk/3 - 1) + oys[kk];
    float qx = (float)(w + kk%3 - 1) + oxs[kk];
    float fy = floorf(py), fx = floorf(qx);
    float ty = py - fy, tx = qx - fx;
    int y0 = (int)fy, x0 = (int)fx;
    int y1 = y0 + 1,  x1 = x0 + 1;
    bool vy0 = (y0>=0)&&(y0<Hh), vy1 = (y1>=0)&&(y1<Hh);
    bool vx0 = (x0>=0)&&(x0<Ww), vx1 = (x1>=0)&&(x1<Ww);
    int yc0 = min(max(y0,0),Hh-1)*Ww, yc1 = min(max(y1,0),Hh-1)*Ww;
    int xc0 = min(max(x0,0),Ww-1),    xc1 = min(max(x1,0),Ww-1);
    int s00 = (yc0 + xc0)*Cc + lane*2, s01 = (yc0 + xc1)*Cc + lane*2;
    int s10 = (yc1 + xc0)*Cc + lane*2, s11 = (yc1 + xc1)*Cc + lane*2;
    float cf0 = (vy0&&vx0) ? (1.f-ty)*(1.f-tx) : 0.f;
    float cf1 = (vy0&&vx1) ? (1.f-ty)*tx       : 0.f;
    float cf2 = (vy1&&vx0) ? ty*(1.f-tx)       : 0.f;
    float cf3 = (vy1&&vx1) ? ty*tx             : 0.f;
    float2 v00 = *(const float2*)(xb + s00);
    float2 v01 = *(const float2*)(xb + s01);
    float2 v10 = *(const float2*)(xb + s10);
    float2 v11 = *(const float2*)(xb + s11);
    float s0 = cf0*v00.x; s0 = fmaf(cf1, v01.x, s0); s0 = fmaf(cf2, v10.x, s0); s0 = fmaf(cf3, v11.x, s0);
    float s1 = cf0*v00.y; s1 = fmaf(cf1, v01.y, s1); s1 = fmaf(cf2, v10.y, s1); s1 = fmaf(cf3, v11.y, s1);
    acc0 = fmaf(wk[kk].x, s0, acc0);
    acc1 = fmaf(wk[kk].y, s1, acc1);
  }

  *(float2*)&pivot[wid][lane*2] = make_float2(acc0, acc1);
  __syncthreads();
  if (tid < 128){
    int c = tid;
    int bs  = px0 >> 14;
    int hw0 = px0 & 16383;
    float4 r = make_float4(pivot[0][c], pivot[1][c], pivot[2][c], pivot[3][c]);
    *(float4*)(out + ((size_t)bs*Cc + c)*HW + hw0) = r;
  }
}

// ---------------- Fallback (small ws): planar offsets path (R3 kernels) ----------------
__global__ __launch_bounds__(256) void k_comb_pl(const float* __restrict__ part, const float* __restrict__ b_off,
                                                 float* __restrict__ off){
  int f = blockIdx.x*256 + threadIdx.x;
  int o = (f >> 12) % NOFF;
  float4 a = ((const float4*)part)[f];
  float4 c = ((const float4*)(part + (size_t)Bb*NOFF*HW))[f];
  float bo = b_off[o];
  float4 r; r.x=a.x+c.x+bo; r.y=a.y+c.y+bo; r.z=a.z+c.z+bo; r.w=a.w+c.w+bo;
  ((float4*)off)[f] = r;
}

__global__ __launch_bounds__(256) void k_deform_pl(const float* __restrict__ x, const float* __restrict__ off,
                                                   const float* __restrict__ w_dw, float* __restrict__ out){
  int tid = threadIdx.x;
  int cg = blockIdx.x & 1;
  int pblk = blockIdx.x >> 1;
  int px = tid & 63, g = tid >> 6;
  int gu = __builtin_amdgcn_readfirstlane(g);
  int idx = pblk*64 + px;
  int b = idx >> 14; int rem = idx & 16383; int h = rem >> 7; int w = rem & 127;

  const float* offb = off + (size_t)b*NOFF*HW + rem;
  int ch0 = cg*64 + gu*16;
  const float* xb  = x   + ((size_t)b*Cc + ch0)*HW;
  float*       ob  = out + ((size_t)b*Cc + ch0)*HW;
  const float* wdw = w_dw + ch0*9;

  float oy[9], ox[9];
  #pragma unroll
  for (int kk=0;kk<9;kk++){
    oy[kk] = offb[(size_t)(2*kk)*HW];
    ox[kk] = offb[(size_t)(2*kk+1)*HW];
  }
  int iob[9][4]; float cf[9][4];
  #pragma unroll
  for (int kk=0;kk<9;kk++){
    float py = (float)(h + kk/3 - 1) + oy[kk];
    float qx = (float)(w + kk%3 - 1) + ox[kk];
    float fy = floorf(py), fx = floorf(qx);
    float ty = py - fy, tx = qx - fx;
    int y0 = (int)fy, x0 = (int)fx;
    int y1 = y0 + 1,  x1 = x0 + 1;
    bool vy0 = (y0>=0)&&(y0<Hh), vy1 = (y1>=0)&&(y1<Hh);
    bool vx0 = (x0>=0)&&(x0<Ww), vx1 = (x1>=0)&&(x1<Ww);
    int yc0 = min(max(y0,0),Hh-1)*Ww, yc1 = min(max(y1,0),Hh-1)*Ww;
    int xc0 = min(max(x0,0),Ww-1),    xc1 = min(max(x1,0),Ww-1);
    iob[kk][0] = (yc0 + xc0)*4; iob[kk][1] = (yc0 + xc1)*4;
    iob[kk][2] = (yc1 + xc0)*4; iob[kk][3] = (yc1 + xc1)*4;
    cf[kk][0] = (vy0&&vx0) ? (1.f-ty)*(1.f-tx) : 0.f;
    cf[kk][1] = (vy0&&vx1) ? (1.f-ty)*tx       : 0.f;
    cf[kk][2] = (vy1&&vx0) ? ty*(1.f-tx)       : 0.f;
    cf[kk][3] = (vy1&&vx1) ? ty*tx             : 0.f;
  }
  #pragma unroll 2
  for (int ci=0;ci<16;ci++){
    const char* xc = (const char*)(xb + (size_t)ci*HW);
    float v[9][4];
    #pragma unroll
    for (int kk=0;kk<9;kk++)
      #pragma unroll
      for (int j=0;j<4;j++)
        v[kk][j] = *(const float*)(xc + iob[kk][j]);
    float o = 0.f;
    #pragma unroll
    for (int kk=0;kk<9;kk++){
      float s =       cf[kk][0]*v[kk][0];
      s = fmaf(cf[kk][1], v[kk][1], s);
      s = fmaf(cf[kk][2], v[kk][2], s);
      s = fmaf(cf[kk][3], v[kk][3], s);
      o = fmaf(wdw[ci*9+kk], s, o);
    }
    ob[(size_t)ci*HW + rem] = o;
  }
}

// ---------------- K2b: per-(channel,batch) partial sums ----------------
__global__ __launch_bounds__(256) void k_stats1(const float* __restrict__ dw, float* __restrict__ ps){
  int c = blockIdx.x >> 3, b = blockIdx.x & 7;
  const float4* p = (const float4*)(dw + ((size_t)b*Cc + c)*HW);
  float s = 0.f, s2 = 0.f;
  for (int i=threadIdx.x; i<HW/4; i+=256){
    float4 v = p[i];
    s += v.x + v.y + v.z + v.w;
    s2 = fmaf(v.x, v.x, s2); s2 = fmaf(v.y, v.y, s2);
    s2 = fmaf(v.z, v.z, s2); s2 = fmaf(v.w, v.w, s2);
  }
  #pragma unroll
  for (int d=32; d>0; d>>=1){ s += __shfl_down(s, d, 64); s2 += __shfl_down(s2, d, 64); }
  __shared__ float ls[4], ls2[4];
  int lane = threadIdx.x & 63, wid = threadIdx.x >> 6;
  if (lane==0){ ls[wid]=s; ls2[wid]=s2; }
  __syncthreads();
  if (threadIdx.x==0){
    float S=0.f, S2=0.f;
    #pragma unroll
    for (int i=0;i<4;i++){ S+=ls[i]; S2+=ls2[i]; }
    ps[c*8+b] = S;
    ps[1024 + c*8+b] = S2;
  }
}

// ---------------- K2c: finalize mean/rstd ----------------
__global__ __launch_bounds__(128) void k_stats2(const float* __restrict__ ps, float* __restrict__ mr){
  int c = threadIdx.x;
  float S=0.f, S2=0.f;
  #pragma unroll
  for (int b=0;b<8;b++){ S += ps[c*8+b]; S2 += ps[1024 + c*8+b]; }
  const float invN = 1.f/(float)(Bb*HW);
  float m = S*invN;
  float var = S2*invN - m*m;
  mr[c]      = m;
  mr[Cc + c] = rsqrtf(var + 1e-5f);
}

// ---------------- K3: in-place BN-apply + SiLU + residual (float4) ----------------
__global__ __launch_bounds__(256) void k_apply(float* __restrict__ out, const float* __restrict__ x,
                                               const float* __restrict__ mr, const float* __restrict__ gamma,
                                               const float* __restrict__ beta){
  int i = blockIdx.x*256 + threadIdx.x;
  int c = (i >> 12) & 127;
  float4 v  = ((const float4*)out)[i];
  float4 xi = ((const float4*)x)[i];
  float m = mr[c], r = mr[Cc+c], g = gamma[c], be = beta[c];
  float* vp = (float*)&v; const float* xp = (const float*)&xi;
  float4 o; float* op = (float*)&o;
  #pragma unroll
  for (int j=0;j<4;j++){
    float t = (vp[j]-m)*r*g + be;
    t = t / (1.f + expf(-t));
    op[j] = t + xp[j];
  }
  ((float4*)out)[i] = o;
}

extern "C" void kernel_launch(void* const* d_in, const int* in_sizes, int n_in,
                              void* d_out, int out_size, void* d_ws, size_t ws_size,
                              hipStream_t stream) {
  const float* x     = (const float*)d_in[0];
  const float* w_off = (const float*)d_in[1];
  const float* b_off = (const float*)d_in[2];
  const float* w_dw  = (const float*)d_in[3];
  const float* gamma = (const float*)d_in[4];
  const float* beta  = (const float*)d_in[5];
  float* out = (float*)d_out;

  float* wp2 = (float*)d_ws;                 // 23040
  float* wdt = wp2 + 23040;                  // 1152
  float* mr  = wp2 + 24576;                  // 256
  float* ps  = mr + 256;                     // 2048
  float* offx = wp2 + 32768;                 // big: [NPIX][20] = 2,621,440
  float* xt   = offx + (size_t)NPIX*20;      // big: NHWC x = 16,777,216

  const size_t NEED = ((size_t)32768 + (size_t)NPIX*20 + (size_t)NPIX*Cc) * 4;
  bool big = (ws_size >= NEED);

  hipLaunchKernelGGL(k_repack, dim3((Cc*9*20 + 9*Cc + 255)/256), dim3(256), 0, stream, w_off, w_dw, wp2, wdt);
  hipLaunchKernelGGL(k_offset, dim3(512), dim3(256), 0, stream, x, wp2, out);   // partials -> d_out

  if (big){
    hipLaunchKernelGGL(k_tx,       dim3(2048),     dim3(256), 0, stream, x, xt);
    hipLaunchKernelGGL(k_comb_nx,  dim3(NPIX/256), dim3(256), 0, stream, out, b_off, offx);
    hipLaunchKernelGGL(k_deform_nx,dim3(NPIX/4),   dim3(256), 0, stream, xt, offx, wdt, out);
  } else {
    float* off = wp2 + 32768;               // planar offsets fit the old ws footprint
    hipLaunchKernelGGL(k_comb_pl,  dim3(Bb*NOFF*HW/4/256), dim3(256), 0, stream, out, b_off, off);
    hipLaunchKernelGGL(k_deform_pl,dim3(4096), dim3(256), 0, stream, x, off, w_dw, out);
  }

  hipLaunchKernelGGL(k_stats1, dim3(Cc*Bb), dim3(256), 0, stream, out, ps);
  hipLaunchKernelGGL(k_stats2, dim3(1),     dim3(128), 0, stream, ps, mr);
  hipLaunchKernelGGL(k_apply,  dim3(NPIX*Cc/4/256), dim3(256), 0, stream, out, x, mr, gamma, beta);
}

// Round 6
// 309.467 us; speedup vs baseline: 3.0165x; 1.1131x over previous
//
#include <hip/hip_runtime.h>
#include <hip/hip_fp16.h>
#include <math.h>

#define Cc 128
#define Hh 128
#define Ww 128
#define Bb 8
#define HW 16384
#define NPIX 131072   // B*H*W
#define NOFF 18

typedef unsigned int u32;

// ---------------- K0: repack offset-conv weights [c][k][o(pad20)] + w_dw transpose [k][c] ----------------
__global__ __launch_bounds__(256) void k_repack(const float* __restrict__ w_off, const float* __restrict__ w_dw,
                                                float* __restrict__ wp2, float* __restrict__ wdt){
  int i = blockIdx.x*256 + threadIdx.x;
  if (i < Cc*9*20){
    int o = i % 20; int t = i / 20; int k = t % 9; int c = t / 9;
    wp2[i] = (o < NOFF) ? w_off[(o*Cc + c)*9 + k] : 0.f;
  }
  int j = i - Cc*9*20;
  if (j >= 0 && j < 9*Cc){
    int c = j % Cc; int k = j / Cc;
    wdt[j] = w_dw[c*9 + k];
  }
}

// ---------------- K1: offset conv (Cin=128 -> 18, 3x3, pad 1) ----------------
__global__ __launch_bounds__(256) void k_offset(const float* __restrict__ x, const float* __restrict__ wp2,
                                                float* __restrict__ part){
  __shared__ float wlds[64*9*20];
  int tid = threadIdx.x;
  int chalf = blockIdx.x & 1;
  int pb    = blockIdx.x >> 1;
  int colh  = pb & 1;
  int rowg  = (pb >> 1) & 15;
  int b     = pb >> 5;

  {
    const float4* src = (const float4*)(wp2 + chalf*11520);
    float4* dst = (float4*)wlds;
    for (int i = tid; i < 2880; i += 256) dst[i] = src[i];
  }
  __syncthreads();

  int lane = tid & 63, wid = tid >> 6;
  int gr0 = rowg*8 + wid*2;
  int col = colh*64 + lane;

  int rb[4]; float rm[4];
  #pragma unroll
  for (int j=0;j<4;j++){
    int gr = gr0 - 1 + j;
    rm[j] = (gr>=0 && gr<Hh) ? 1.f : 0.f;
    rb[j] = min(max(gr,0),Hh-1)*Ww;
  }
  int cx[3]; float cm[3];
  #pragma unroll
  for (int s=0;s<3;s++){
    int cc = col + s - 1;
    cm[s] = (cc>=0 && cc<Ww) ? 1.f : 0.f;
    cx[s] = min(max(cc,0),Ww-1);
  }
  float mk[4][3];
  #pragma unroll
  for (int j=0;j<4;j++)
    #pragma unroll
    for (int s=0;s<3;s++) mk[j][s] = rm[j]*cm[s];

  float acc[NOFF][2];
  #pragma unroll
  for (int o=0;o<NOFF;o++){ acc[o][0]=0.f; acc[o][1]=0.f; }

  const float* xb = x + ((size_t)(b*Cc + chalf*64))*HW;
  for (int ci=0; ci<64; ci++){
    const float* xc = xb + (size_t)ci*HW;
    float xv[4][3];
    #pragma unroll
    for (int j=0;j<4;j++)
      #pragma unroll
      for (int s=0;s<3;s++) xv[j][s] = xc[rb[j] + cx[s]] * mk[j][s];

    #pragma unroll
    for (int k=0;k<9;k++){
      const float* wk = &wlds[(ci*9 + k)*20];
      float4 wa = *(const float4*)(wk);
      float4 wb = *(const float4*)(wk+4);
      float4 wc = *(const float4*)(wk+8);
      float4 wd = *(const float4*)(wk+12);
      float2 we = *(const float2*)(wk+16);
      int ky = k/3, kx = k%3;
      float xa = xv[ky][kx], xbv = xv[ky+1][kx];
      acc[0][0]  = fmaf(xa, wa.x, acc[0][0]);   acc[0][1]  = fmaf(xbv, wa.x, acc[0][1]);
      acc[1][0]  = fmaf(xa, wa.y, acc[1][0]);   acc[1][1]  = fmaf(xbv, wa.y, acc[1][1]);
      acc[2][0]  = fmaf(xa, wa.z, acc[2][0]);   acc[2][1]  = fmaf(xbv, wa.z, acc[2][1]);
      acc[3][0]  = fmaf(xa, wa.w, acc[3][0]);   acc[3][1]  = fmaf(xbv, wa.w, acc[3][1]);
      acc[4][0]  = fmaf(xa, wb.x, acc[4][0]);   acc[4][1]  = fmaf(xbv, wb.x, acc[4][1]);
      acc[5][0]  = fmaf(xa, wb.y, acc[5][0]);   acc[5][1]  = fmaf(xbv, wb.y, acc[5][1]);
      acc[6][0]  = fmaf(xa, wb.z, acc[6][0]);   acc[6][1]  = fmaf(xbv, wb.z, acc[6][1]);
      acc[7][0]  = fmaf(xa, wb.w, acc[7][0]);   acc[7][1]  = fmaf(xbv, wb.w, acc[7][1]);
      acc[8][0]  = fmaf(xa, wc.x, acc[8][0]);   acc[8][1]  = fmaf(xbv, wc.x, acc[8][1]);
      acc[9][0]  = fmaf(xa, wc.y, acc[9][0]);   acc[9][1]  = fmaf(xbv, wc.y, acc[9][1]);
      acc[10][0] = fmaf(xa, wc.z, acc[10][0]);  acc[10][1] = fmaf(xbv, wc.z, acc[10][1]);
      acc[11][0] = fmaf(xa, wc.w, acc[11][0]);  acc[11][1] = fmaf(xbv, wc.w, acc[11][1]);
      acc[12][0] = fmaf(xa, wd.x, acc[12][0]);  acc[12][1] = fmaf(xbv, wd.x, acc[12][1]);
      acc[13][0] = fmaf(xa, wd.y, acc[13][0]);  acc[13][1] = fmaf(xbv, wd.y, acc[13][1]);
      acc[14][0] = fmaf(xa, wd.z, acc[14][0]);  acc[14][1] = fmaf(xbv, wd.z, acc[14][1]);
      acc[15][0] = fmaf(xa, wd.w, acc[15][0]);  acc[15][1] = fmaf(xbv, wd.w, acc[15][1]);
      acc[16][0] = fmaf(xa, we.x, acc[16][0]);  acc[16][1] = fmaf(xbv, we.x, acc[16][1]);
      acc[17][0] = fmaf(xa, we.y, acc[17][0]);  acc[17][1] = fmaf(xbv, we.y, acc[17][1]);
    }
  }

  float* pp = part + ((size_t)(chalf*Bb + b)*NOFF)*HW + gr0*Ww + col;
  #pragma unroll
  for (int o=0;o<NOFF;o++){
    pp[(size_t)o*HW]       = acc[o][0];
    pp[(size_t)o*HW + Ww]  = acc[o][1];
  }
}

// ---------------- K_tx: transpose x NCHW -> NHWC (LDS-tiled) ----------------
__global__ __launch_bounds__(256) void k_tx(const float* __restrict__ x, float* __restrict__ xt){
  __shared__ float t[128][65];
  int tid = threadIdx.x;
  int b   = blockIdx.x >> 8;
  int hw0 = (blockIdx.x & 255) << 6;
  int lane = tid & 63, wg = tid >> 6;
  const float* xb = x + (size_t)b*Cc*HW;
  #pragma unroll
  for (int k=0;k<32;k++){
    int c = wg + k*4;
    t[c][lane] = xb[(size_t)c*HW + hw0 + lane];
  }
  __syncthreads();
  float* ob = xt + ((size_t)b*HW + hw0)*Cc;
  int c2 = tid & 127, half = tid >> 7;
  #pragma unroll
  for (int k=0;k<32;k++){
    int hwl = half + k*2;
    ob[(size_t)hwl*Cc + c2] = t[c2][hwl];
  }
}

// ---------------- K_rec: per-pixel sample records (u16 idx + fp16 coef, 36 dwords) ----------------
__global__ __launch_bounds__(256) void k_rec(const float* __restrict__ part, const float* __restrict__ b_off,
                                             u32* __restrict__ recs){
  int px = blockIdx.x*256 + threadIdx.x;
  int b = px >> 14, hw = px & 16383;
  int h = hw >> 7, w = hw & 127;
  float v[NOFF];
  #pragma unroll
  for (int o=0;o<NOFF;o++){
    float a = part[((size_t)(b)*NOFF + o)*HW + hw];
    float c = part[((size_t)(Bb + b)*NOFF + o)*HW + hw];
    v[o] = a + c + b_off[o];
  }
  u32 rec[36];
  #pragma unroll
  for (int kk=0;kk<9;kk++){
    float py = (float)(h + kk/3 - 1) + v[2*kk];
    float qx = (float)(w + kk%3 - 1) + v[2*kk+1];
    float fy = floorf(py), fx = floorf(qx);
    float ty = py - fy, tx = qx - fx;
    int y0 = (int)fy, x0 = (int)fx;
    int y1 = y0+1, x1 = x0+1;
    bool vy0 = (y0>=0)&&(y0<Hh), vy1=(y1>=0)&&(y1<Hh);
    bool vx0 = (x0>=0)&&(x0<Ww), vx1=(x1>=0)&&(x1<Ww);
    u32 yc0 = (u32)(min(max(y0,0),Hh-1)*Ww), yc1 = (u32)(min(max(y1,0),Hh-1)*Ww);
    u32 xc0 = (u32)min(max(x0,0),Ww-1),      xc1 = (u32)min(max(x1,0),Ww-1);
    rec[2*kk]   = (yc0+xc0) | ((yc0+xc1)<<16);
    rec[2*kk+1] = (yc1+xc0) | ((yc1+xc1)<<16);
    float c00 = (vy0&&vx0) ? (1.f-ty)*(1.f-tx) : 0.f;
    float c01 = (vy0&&vx1) ? (1.f-ty)*tx       : 0.f;
    float c10 = (vy1&&vx0) ? ty*(1.f-tx)       : 0.f;
    float c11 = (vy1&&vx1) ? ty*tx             : 0.f;
    __half2 hA = __floats2half2_rn(c00, c01);
    __half2 hB = __floats2half2_rn(c10, c11);
    rec[18+2*kk] = *(u32*)&hA;
    rec[19+2*kk] = *(u32*)&hB;
  }
  uint4* dst = (uint4*)(recs + (size_t)px*36);
  #pragma unroll
  for (int q=0;q<9;q++) dst[q] = *(uint4*)(rec + q*4);
}

// ---------------- K2: deformable depthwise; scalar records, NHWC reads, 16px pivot ----------------
__global__ __launch_bounds__(256) void k_deform_rec(const float* __restrict__ xt, const u32* __restrict__ recs,
                                                    const float* __restrict__ wdt, float* __restrict__ out){
  __shared__ float pivot[16][132];
  int tid = threadIdx.x, lane = tid & 63, wid = tid >> 6;
  int pxb = blockIdx.x * 16;
  int bu = pxb >> 14, hw0 = pxb & 16383;
  int l2 = lane*2;

  float2 wk[9];
  #pragma unroll
  for (int k=0;k<9;k++) wk[k] = *(const float2*)(wdt + k*Cc + l2);

  const float* xbu = xt + (size_t)bu*HW*Cc;

  #pragma unroll
  for (int i=0;i<4;i++){
    int pu = __builtin_amdgcn_readfirstlane(pxb + wid*4 + i);
    const u32* rec = recs + (size_t)pu*36;
    float acc0 = 0.f, acc1 = 0.f;
    #pragma unroll
    for (int kk=0;kk<9;kk++){
      u32 dA = rec[2*kk], dB = rec[2*kk+1];
      u32 uA = rec[18+2*kk], uB = rec[19+2*kk];
      __half2 hA = *(__half2*)&uA, hB = *(__half2*)&uB;
      float c00 = __low2float(hA), c01 = __high2float(hA);
      float c10 = __low2float(hB), c11 = __high2float(hB);
      float2 v00 = *(const float2*)(xbu + (size_t)(dA & 0xFFFFu)*Cc + l2);
      float2 v01 = *(const float2*)(xbu + (size_t)(dA >> 16)*Cc + l2);
      float2 v10 = *(const float2*)(xbu + (size_t)(dB & 0xFFFFu)*Cc + l2);
      float2 v11 = *(const float2*)(xbu + (size_t)(dB >> 16)*Cc + l2);
      float s0 = c00*v00.x; s0 = fmaf(c01, v01.x, s0); s0 = fmaf(c10, v10.x, s0); s0 = fmaf(c11, v11.x, s0);
      float s1 = c00*v00.y; s1 = fmaf(c01, v01.y, s1); s1 = fmaf(c10, v10.y, s1); s1 = fmaf(c11, v11.y, s1);
      acc0 = fmaf(wk[kk].x, s0, acc0);
      acc1 = fmaf(wk[kk].y, s1, acc1);
    }
    pivot[wid*4+i][l2]   = acc0;
    pivot[wid*4+i][l2+1] = acc1;
  }
  __syncthreads();
  #pragma unroll
  for (int it=0; it<2; it++){
    int c = (tid>>2) + it*64, q = tid & 3;
    float4 r = make_float4(pivot[q*4+0][c], pivot[q*4+1][c], pivot[q*4+2][c], pivot[q*4+3][c]);
    *(float4*)(out + ((size_t)bu*Cc + c)*HW + hw0 + q*4) = r;
  }
}

// ---------------- R5 fallback kernels (planar-record path) ----------------
__global__ __launch_bounds__(256) void k_comb_nx(const float* __restrict__ part, const float* __restrict__ b_off,
                                                 float* __restrict__ offx){
  int px = blockIdx.x*256 + threadIdx.x;
  int b = px >> 14, hw = px & 16383;
  float v[20];
  #pragma unroll
  for (int o=0;o<NOFF;o++){
    float a = part[((size_t)(b)*NOFF + o)*HW + hw];
    float c = part[((size_t)(Bb + b)*NOFF + o)*HW + hw];
    v[o] = a + c + b_off[o];
  }
  v[18] = 0.f; v[19] = 0.f;
  float* dst = offx + (size_t)px*20;
  #pragma unroll
  for (int q=0;q<5;q++)
    *(float4*)(dst + q*4) = *(float4*)(v + q*4);
}

__global__ __launch_bounds__(256) void k_deform_nx(const float* __restrict__ xt, const float* __restrict__ offx,
                                                   const float* __restrict__ wdt, float* __restrict__ out){
  __shared__ float pivot[4][128];
  int tid = threadIdx.x;
  int lane = tid & 63, wid = tid >> 6;
  int px0 = blockIdx.x << 2;
  int pu  = __builtin_amdgcn_readfirstlane(px0 + wid);
  int bu  = pu >> 14;
  int rem = pu & 16383;
  int h = rem >> 7, w = rem & 127;

  const float4* op = (const float4*)(offx + (size_t)pu*20);
  float4 a0 = op[0], a1 = op[1], a2 = op[2], a3 = op[3];
  float4 a4 = op[4];

  float2 wk[9];
  #pragma unroll
  for (int k=0;k<9;k++) wk[k] = *(const float2*)(wdt + k*Cc + lane*2);

  const float* xb = xt + (size_t)bu*HW*Cc;
  float acc0 = 0.f, acc1 = 0.f;

  float oys[9] = {a0.x,a0.z,a1.x,a1.z,a2.x,a2.z,a3.x,a3.z,a4.x};
  float oxs[9] = {a0.y,a0.w,a1.y,a1.w,a2.y,a2.w,a3.y,a3.w,a4.y};

  #pragma unroll
  for (int kk=0;kk<9;kk++){
    float py = (float)(h + kk/3 - 1) + oys[kk];
    float qx = (float)(w + kk%3 - 1) + oxs[kk];
    float fy = floorf(py), fx = floorf(qx);
    float ty = py - fy, tx = qx - fx;
    int y0 = (int)fy, x0 = (int)fx;
    int y1 = y0 + 1,  x1 = x0 + 1;
    bool vy0 = (y0>=0)&&(y0<Hh), vy1 = (y1>=0)&&(y1<Hh);
    bool vx0 = (x0>=0)&&(x0<Ww), vx1 = (x1>=0)&&(x1<Ww);
    int yc0 = min(max(y0,0),Hh-1)*Ww, yc1 = min(max(y1,0),Hh-1)*Ww;
    int xc0 = min(max(x0,0),Ww-1),    xc1 = min(max(x1,0),Ww-1);
    int s00 = (yc0 + xc0)*Cc + lane*2, s01 = (yc0 + xc1)*Cc + lane*2;
    int s10 = (yc1 + xc0)*Cc + lane*2, s11 = (yc1 + xc1)*Cc + lane*2;
    float cf0 = (vy0&&vx0) ? (1.f-ty)*(1.f-tx) : 0.f;
    float cf1 = (vy0&&vx1) ? (1.f-ty)*tx       : 0.f;
    float cf2 = (vy1&&vx0) ? ty*(1.f-tx)       : 0.f;
    float cf3 = (vy1&&vx1) ? ty*tx             : 0.f;
    float2 v00 = *(const float2*)(xb + s00);
    float2 v01 = *(const float2*)(xb + s01);
    float2 v10 = *(const float2*)(xb + s10);
    float2 v11 = *(const float2*)(xb + s11);
    float s0 = cf0*v00.x; s0 = fmaf(cf1, v01.x, s0); s0 = fmaf(cf2, v10.x, s0); s0 = fmaf(cf3, v11.x, s0);
    float s1 = cf0*v00.y; s1 = fmaf(cf1, v01.y, s1); s1 = fmaf(cf2, v10.y, s1); s1 = fmaf(cf3, v11.y, s1);
    acc0 = fmaf(wk[kk].x, s0, acc0);
    acc1 = fmaf(wk[kk].y, s1, acc1);
  }

  *(float2*)&pivot[wid][lane*2] = make_float2(acc0, acc1);
  __syncthreads();
  if (tid < 128){
    int c = tid;
    int bs  = px0 >> 14;
    int hw0 = px0 & 16383;
    float4 r = make_float4(pivot[0][c], pivot[1][c], pivot[2][c], pivot[3][c]);
    *(float4*)(out + ((size_t)bs*Cc + c)*HW + hw0) = r;
  }
}

// ---------------- stats + apply ----------------
__global__ __launch_bounds__(256) void k_stats1(const float* __restrict__ dw, float* __restrict__ ps){
  int c = blockIdx.x >> 3, b = blockIdx.x & 7;
  const float4* p = (const float4*)(dw + ((size_t)b*Cc + c)*HW);
  float s = 0.f, s2 = 0.f;
  for (int i=threadIdx.x; i<HW/4; i+=256){
    float4 v = p[i];
    s += v.x + v.y + v.z + v.w;
    s2 = fmaf(v.x, v.x, s2); s2 = fmaf(v.y, v.y, s2);
    s2 = fmaf(v.z, v.z, s2); s2 = fmaf(v.w, v.w, s2);
  }
  #pragma unroll
  for (int d=32; d>0; d>>=1){ s += __shfl_down(s, d, 64); s2 += __shfl_down(s2, d, 64); }
  __shared__ float ls[4], ls2[4];
  int lane = threadIdx.x & 63, wid = threadIdx.x >> 6;
  if (lane==0){ ls[wid]=s; ls2[wid]=s2; }
  __syncthreads();
  if (threadIdx.x==0){
    float S=0.f, S2=0.f;
    #pragma unroll
    for (int i=0;i<4;i++){ S+=ls[i]; S2+=ls2[i]; }
    ps[c*8+b] = S;
    ps[1024 + c*8+b] = S2;
  }
}

__global__ __launch_bounds__(128) void k_stats2(const float* __restrict__ ps, float* __restrict__ mr){
  int c = threadIdx.x;
  float S=0.f, S2=0.f;
  #pragma unroll
  for (int b=0;b<8;b++){ S += ps[c*8+b]; S2 += ps[1024 + c*8+b]; }
  const float invN = 1.f/(float)(Bb*HW);
  float m = S*invN;
  float var = S2*invN - m*m;
  mr[c]      = m;
  mr[Cc + c] = rsqrtf(var + 1e-5f);
}

__global__ __launch_bounds__(256) void k_apply(float* __restrict__ out, const float* __restrict__ x,
                                               const float* __restrict__ mr, const float* __restrict__ gamma,
                                               const float* __restrict__ beta){
  int i = blockIdx.x*256 + threadIdx.x;
  int c = (i >> 12) & 127;
  float4 v  = ((const float4*)out)[i];
  float4 xi = ((const float4*)x)[i];
  float m = mr[c], r = mr[Cc+c], g = gamma[c], be = beta[c];
  float* vp = (float*)&v; const float* xp = (const float*)&xi;
  float4 o; float* op = (float*)&o;
  #pragma unroll
  for (int j=0;j<4;j++){
    float t = (vp[j]-m)*r*g + be;
    t = t / (1.f + expf(-t));
    op[j] = t + xp[j];
  }
  ((float4*)out)[i] = o;
}

extern "C" void kernel_launch(void* const* d_in, const int* in_sizes, int n_in,
                              void* d_out, int out_size, void* d_ws, size_t ws_size,
                              hipStream_t stream) {
  const float* x     = (const float*)d_in[0];
  const float* w_off = (const float*)d_in[1];
  const float* b_off = (const float*)d_in[2];
  const float* w_dw  = (const float*)d_in[3];
  const float* gamma = (const float*)d_in[4];
  const float* beta  = (const float*)d_in[5];
  float* out = (float*)d_out;

  float* wp2 = (float*)d_ws;                 // 23040
  float* wdt = wp2 + 23040;                  // 1152
  float* mr  = wp2 + 24576;                  // 256
  float* ps  = mr + 256;                     // 2048

  // path A (records): recs = NPIX*36 dwords, xt = NPIX*128 floats
  u32*   recs = (u32*)(wp2 + 32768);
  float* xtA  = wp2 + 32768 + (size_t)NPIX*36;
  const size_t NEED_A = ((size_t)32768 + (size_t)NPIX*36 + (size_t)NPIX*Cc) * 4;

  // path B (R5): offx = NPIX*20, xt = NPIX*128
  float* offx = wp2 + 32768;
  float* xtB  = offx + (size_t)NPIX*20;
  const size_t NEED_B = ((size_t)32768 + (size_t)NPIX*20 + (size_t)NPIX*Cc) * 4;

  hipLaunchKernelGGL(k_repack, dim3((Cc*9*20 + 9*Cc + 255)/256), dim3(256), 0, stream, w_off, w_dw, wp2, wdt);
  hipLaunchKernelGGL(k_offset, dim3(512), dim3(256), 0, stream, x, wp2, out);   // partials -> d_out

  if (ws_size >= NEED_A){
    hipLaunchKernelGGL(k_tx,         dim3(2048),     dim3(256), 0, stream, x, xtA);
    hipLaunchKernelGGL(k_rec,        dim3(NPIX/256), dim3(256), 0, stream, out, b_off, recs);
    hipLaunchKernelGGL(k_deform_rec, dim3(NPIX/16),  dim3(256), 0, stream, xtA, recs, wdt, out);
  } else {
    hipLaunchKernelGGL(k_tx,        dim3(2048),     dim3(256), 0, stream, x, xtB);
    hipLaunchKernelGGL(k_comb_nx,   dim3(NPIX/256), dim3(256), 0, stream, out, b_off, offx);
    hipLaunchKernelGGL(k_deform_nx, dim3(NPIX/4),   dim3(256), 0, stream, xtB, offx, wdt, out);
  }

  hipLaunchKernelGGL(k_stats1, dim3(Cc*Bb), dim3(256), 0, stream, out, ps);
  hipLaunchKernelGGL(k_stats2, dim3(1),     dim3(128), 0, stream, ps, mr);
  hipLaunchKernelGGL(k_apply,  dim3(NPIX*Cc/4/256), dim3(256), 0, stream, out, x, mr, gamma, beta);
}

// Round 7
// 221.210 us; speedup vs baseline: 4.2200x; 1.3990x over previous
//
#include <hip/hip_runtime.h>
#include <hip/hip_fp16.h>
#include <math.h>

#define Cc 128
#define Hh 128
#define Ww 128
#define Bb 8
#define HW 16384
#define NPIX 131072   // B*H*W
#define NOFF 18

typedef unsigned int u32;

static __device__ __forceinline__ u32 f2bf(float f){
  u32 u = __float_as_uint(f);
  return (u + 0x7fffu + ((u >> 16) & 1u)) >> 16;   // RNE
}

// ---------------- K0: repack offset-conv weights [c][k][o(pad20)] + w_dw transpose [k][c] ----------------
__global__ __launch_bounds__(256) void k_repack(const float* __restrict__ w_off, const float* __restrict__ w_dw,
                                                float* __restrict__ wp2, float* __restrict__ wdt){
  int i = blockIdx.x*256 + threadIdx.x;
  if (i < Cc*9*20){
    int o = i % 20; int t = i / 20; int k = t % 9; int c = t / 9;
    wp2[i] = (o < NOFF) ? w_off[(o*Cc + c)*9 + k] : 0.f;
  }
  int j = i - Cc*9*20;
  if (j >= 0 && j < 9*Cc){
    int c = j % Cc; int k = j / Cc;
    wdt[j] = w_dw[c*9 + k];
  }
}

// ---------------- K1: offset conv (Cin=128 -> 18, 3x3, pad 1) ----------------
__global__ __launch_bounds__(256) void k_offset(const float* __restrict__ x, const float* __restrict__ wp2,
                                                float* __restrict__ part){
  __shared__ float wlds[64*9*20];
  int tid = threadIdx.x;
  int chalf = blockIdx.x & 1;
  int pb    = blockIdx.x >> 1;
  int colh  = pb & 1;
  int rowg  = (pb >> 1) & 15;
  int b     = pb >> 5;

  {
    const float4* src = (const float4*)(wp2 + chalf*11520);
    float4* dst = (float4*)wlds;
    for (int i = tid; i < 2880; i += 256) dst[i] = src[i];
  }
  __syncthreads();

  int lane = tid & 63, wid = tid >> 6;
  int gr0 = rowg*8 + wid*2;
  int col = colh*64 + lane;

  int rb[4]; float rm[4];
  #pragma unroll
  for (int j=0;j<4;j++){
    int gr = gr0 - 1 + j;
    rm[j] = (gr>=0 && gr<Hh) ? 1.f : 0.f;
    rb[j] = min(max(gr,0),Hh-1)*Ww;
  }
  int cx[3]; float cm[3];
  #pragma unroll
  for (int s=0;s<3;s++){
    int cc = col + s - 1;
    cm[s] = (cc>=0 && cc<Ww) ? 1.f : 0.f;
    cx[s] = min(max(cc,0),Ww-1);
  }
  float mk[4][3];
  #pragma unroll
  for (int j=0;j<4;j++)
    #pragma unroll
    for (int s=0;s<3;s++) mk[j][s] = rm[j]*cm[s];

  float acc[NOFF][2];
  #pragma unroll
  for (int o=0;o<NOFF;o++){ acc[o][0]=0.f; acc[o][1]=0.f; }

  const float* xb = x + ((size_t)(b*Cc + chalf*64))*HW;
  for (int ci=0; ci<64; ci++){
    const float* xc = xb + (size_t)ci*HW;
    float xv[4][3];
    #pragma unroll
    for (int j=0;j<4;j++)
      #pragma unroll
      for (int s=0;s<3;s++) xv[j][s] = xc[rb[j] + cx[s]] * mk[j][s];

    #pragma unroll
    for (int k=0;k<9;k++){
      const float* wk = &wlds[(ci*9 + k)*20];
      float4 wa = *(const float4*)(wk);
      float4 wb = *(const float4*)(wk+4);
      float4 wc = *(const float4*)(wk+8);
      float4 wd = *(const float4*)(wk+12);
      float2 we = *(const float2*)(wk+16);
      int ky = k/3, kx = k%3;
      float xa = xv[ky][kx], xbv = xv[ky+1][kx];
      acc[0][0]  = fmaf(xa, wa.x, acc[0][0]);   acc[0][1]  = fmaf(xbv, wa.x, acc[0][1]);
      acc[1][0]  = fmaf(xa, wa.y, acc[1][0]);   acc[1][1]  = fmaf(xbv, wa.y, acc[1][1]);
      acc[2][0]  = fmaf(xa, wa.z, acc[2][0]);   acc[2][1]  = fmaf(xbv, wa.z, acc[2][1]);
      acc[3][0]  = fmaf(xa, wa.w, acc[3][0]);   acc[3][1]  = fmaf(xbv, wa.w, acc[3][1]);
      acc[4][0]  = fmaf(xa, wb.x, acc[4][0]);   acc[4][1]  = fmaf(xbv, wb.x, acc[4][1]);
      acc[5][0]  = fmaf(xa, wb.y, acc[5][0]);   acc[5][1]  = fmaf(xbv, wb.y, acc[5][1]);
      acc[6][0]  = fmaf(xa, wb.z, acc[6][0]);   acc[6][1]  = fmaf(xbv, wb.z, acc[6][1]);
      acc[7][0]  = fmaf(xa, wb.w, acc[7][0]);   acc[7][1]  = fmaf(xbv, wb.w, acc[7][1]);
      acc[8][0]  = fmaf(xa, wc.x, acc[8][0]);   acc[8][1]  = fmaf(xbv, wc.x, acc[8][1]);
      acc[9][0]  = fmaf(xa, wc.y, acc[9][0]);   acc[9][1]  = fmaf(xbv, wc.y, acc[9][1]);
      acc[10][0] = fmaf(xa, wc.z, acc[10][0]);  acc[10][1] = fmaf(xbv, wc.z, acc[10][1]);
      acc[11][0] = fmaf(xa, wc.w, acc[11][0]);  acc[11][1] = fmaf(xbv, wc.w, acc[11][1]);
      acc[12][0] = fmaf(xa, wd.x, acc[12][0]);  acc[12][1] = fmaf(xbv, wd.x, acc[12][1]);
      acc[13][0] = fmaf(xa, wd.y, acc[13][0]);  acc[13][1] = fmaf(xbv, wd.y, acc[13][1]);
      acc[14][0] = fmaf(xa, wd.z, acc[14][0]);  acc[14][1] = fmaf(xbv, wd.z, acc[14][1]);
      acc[15][0] = fmaf(xa, wd.w, acc[15][0]);  acc[15][1] = fmaf(xbv, wd.w, acc[15][1]);
      acc[16][0] = fmaf(xa, we.x, acc[16][0]);  acc[16][1] = fmaf(xbv, we.x, acc[16][1]);
      acc[17][0] = fmaf(xa, we.y, acc[17][0]);  acc[17][1] = fmaf(xbv, we.y, acc[17][1]);
    }
  }

  float* pp = part + ((size_t)(chalf*Bb + b)*NOFF)*HW + gr0*Ww + col;
  #pragma unroll
  for (int o=0;o<NOFF;o++){
    pp[(size_t)o*HW]       = acc[o][0];
    pp[(size_t)o*HW + Ww]  = acc[o][1];
  }
}

// ---------------- K_tx: transpose x NCHW -> NHWC, bf16-packed (2 ch per u32) ----------------
__global__ __launch_bounds__(256) void k_tx(const float* __restrict__ x, u32* __restrict__ xt16){
  __shared__ float t[128][65];
  int tid = threadIdx.x;
  int b   = blockIdx.x >> 8;
  int hw0 = (blockIdx.x & 255) << 6;
  int lane = tid & 63, wg = tid >> 6;
  const float* xb = x + (size_t)b*Cc*HW;
  #pragma unroll
  for (int k=0;k<32;k++){
    int c = wg + k*4;
    t[c][lane] = xb[(size_t)c*HW + hw0 + lane];
  }
  __syncthreads();
  u32* ob = xt16 + ((size_t)b*HW + hw0)*64;
  int cpair = tid & 63, grp = tid >> 6;
  #pragma unroll
  for (int k=0;k<16;k++){
    int hwl = grp + k*4;
    float lo = t[cpair*2][hwl];
    float hi = t[cpair*2+1][hwl];
    ob[(size_t)hwl*64 + cpair] = f2bf(lo) | (f2bf(hi) << 16);
  }
}

// ---------------- K_rec: per-pixel sample records (u16 idx + fp16 coef, 36 dwords) ----------------
__global__ __launch_bounds__(256) void k_rec(const float* __restrict__ part, const float* __restrict__ b_off,
                                             u32* __restrict__ recs){
  int px = blockIdx.x*256 + threadIdx.x;
  int b = px >> 14, hw = px & 16383;
  int h = hw >> 7, w = hw & 127;
  float v[NOFF];
  #pragma unroll
  for (int o=0;o<NOFF;o++){
    float a = part[((size_t)(b)*NOFF + o)*HW + hw];
    float c = part[((size_t)(Bb + b)*NOFF + o)*HW + hw];
    v[o] = a + c + b_off[o];
  }
  u32 rec[36];
  #pragma unroll
  for (int kk=0;kk<9;kk++){
    float py = (float)(h + kk/3 - 1) + v[2*kk];
    float qx = (float)(w + kk%3 - 1) + v[2*kk+1];
    float fy = floorf(py), fx = floorf(qx);
    float ty = py - fy, tx = qx - fx;
    int y0 = (int)fy, x0 = (int)fx;
    int y1 = y0+1, x1 = x0+1;
    bool vy0 = (y0>=0)&&(y0<Hh), vy1=(y1>=0)&&(y1<Hh);
    bool vx0 = (x0>=0)&&(x0<Ww), vx1=(x1>=0)&&(x1<Ww);
    u32 yc0 = (u32)(min(max(y0,0),Hh-1)*Ww), yc1 = (u32)(min(max(y1,0),Hh-1)*Ww);
    u32 xc0 = (u32)min(max(x0,0),Ww-1),      xc1 = (u32)min(max(x1,0),Ww-1);
    rec[2*kk]   = (yc0+xc0) | ((yc0+xc1)<<16);
    rec[2*kk+1] = (yc1+xc0) | ((yc1+xc1)<<16);
    float c00 = (vy0&&vx0) ? (1.f-ty)*(1.f-tx) : 0.f;
    float c01 = (vy0&&vx1) ? (1.f-ty)*tx       : 0.f;
    float c10 = (vy1&&vx0) ? ty*(1.f-tx)       : 0.f;
    float c11 = (vy1&&vx1) ? ty*tx             : 0.f;
    __half2 hA = __floats2half2_rn(c00, c01);
    __half2 hB = __floats2half2_rn(c10, c11);
    rec[18+2*kk] = *(u32*)&hA;
    rec[19+2*kk] = *(u32*)&hB;
  }
  uint4* dst = (uint4*)(recs + (size_t)px*36);
  #pragma unroll
  for (int q=0;q<9;q++) dst[q] = *(uint4*)(rec + q*4);
}

// ---------------- K2: deformable depthwise; bf16 NHWC gathers, all-36-loads-in-flight ----------------
__global__ __launch_bounds__(256) void k_deform_rec(const u32* __restrict__ xt, const u32* __restrict__ recs,
                                                    const float* __restrict__ wdt, float* __restrict__ out){
  __shared__ float pivot[16][132];
  int tid = threadIdx.x, lane = tid & 63, wid = tid >> 6;
  int pxb = blockIdx.x * 16;
  int bu = pxb >> 14, hw0 = pxb & 16383;
  int l2 = lane*2;

  float2 wk[9];
  #pragma unroll
  for (int k=0;k<9;k++) wk[k] = *(const float2*)(wdt + k*Cc + l2);

  const u32* xbu = xt + (size_t)bu*HW*64;

  #pragma unroll
  for (int i=0;i<4;i++){
    int pu = __builtin_amdgcn_readfirstlane(pxb + wid*4 + i);
    const u32* rec = recs + (size_t)pu*36;

    // issue all 36 gathers before any use (1 VGPR each; uniform chunk -> SGPR base + lane voffset)
    u32 q[9][4];
    #pragma unroll
    for (int kk=0;kk<9;kk++){
      u32 dA = rec[2*kk], dB = rec[2*kk+1];
      q[kk][0] = xbu[(size_t)(dA & 0xFFFFu)*64 + lane];
      q[kk][1] = xbu[(size_t)(dA >> 16)   *64 + lane];
      q[kk][2] = xbu[(size_t)(dB & 0xFFFFu)*64 + lane];
      q[kk][3] = xbu[(size_t)(dB >> 16)   *64 + lane];
    }

    float acc0 = 0.f, acc1 = 0.f;
    #pragma unroll
    for (int kk=0;kk<9;kk++){
      u32 uA = rec[18+2*kk], uB = rec[19+2*kk];
      __half2 hA = *(__half2*)&uA, hB = *(__half2*)&uB;
      float c00 = __low2float(hA), c01 = __high2float(hA);
      float c10 = __low2float(hB), c11 = __high2float(hB);
      float v0l = __uint_as_float(q[kk][0] << 16), v0h = __uint_as_float(q[kk][0] & 0xffff0000u);
      float v1l = __uint_as_float(q[kk][1] << 16), v1h = __uint_as_float(q[kk][1] & 0xffff0000u);
      float v2l = __uint_as_float(q[kk][2] << 16), v2h = __uint_as_float(q[kk][2] & 0xffff0000u);
      float v3l = __uint_as_float(q[kk][3] << 16), v3h = __uint_as_float(q[kk][3] & 0xffff0000u);
      float s0 = c00*v0l; s0 = fmaf(c01, v1l, s0); s0 = fmaf(c10, v2l, s0); s0 = fmaf(c11, v3l, s0);
      float s1 = c00*v0h; s1 = fmaf(c01, v1h, s1); s1 = fmaf(c10, v2h, s1); s1 = fmaf(c11, v3h, s1);
      acc0 = fmaf(wk[kk].x, s0, acc0);
      acc1 = fmaf(wk[kk].y, s1, acc1);
    }
    pivot[wid*4+i][l2]   = acc0;
    pivot[wid*4+i][l2+1] = acc1;
  }
  __syncthreads();
  #pragma unroll
  for (int it=0; it<2; it++){
    int c = (tid>>2) + it*64, qd = tid & 3;
    float4 r = make_float4(pivot[qd*4+0][c], pivot[qd*4+1][c], pivot[qd*4+2][c], pivot[qd*4+3][c]);
    *(float4*)(out + ((size_t)bu*Cc + c)*HW + hw0 + qd*4) = r;
  }
}

// ---------------- stats + apply ----------------
__global__ __launch_bounds__(256) void k_stats1(const float* __restrict__ dw, float* __restrict__ ps){
  int c = blockIdx.x >> 3, b = blockIdx.x & 7;
  const float4* p = (const float4*)(dw + ((size_t)b*Cc + c)*HW);
  float s = 0.f, s2 = 0.f;
  for (int i=threadIdx.x; i<HW/4; i+=256){
    float4 v = p[i];
    s += v.x + v.y + v.z + v.w;
    s2 = fmaf(v.x, v.x, s2); s2 = fmaf(v.y, v.y, s2);
    s2 = fmaf(v.z, v.z, s2); s2 = fmaf(v.w, v.w, s2);
  }
  #pragma unroll
  for (int d=32; d>0; d>>=1){ s += __shfl_down(s, d, 64); s2 += __shfl_down(s2, d, 64); }
  __shared__ float ls[4], ls2[4];
  int lane = threadIdx.x & 63, wid = threadIdx.x >> 6;
  if (lane==0){ ls[wid]=s; ls2[wid]=s2; }
  __syncthreads();
  if (threadIdx.x==0){
    float S=0.f, S2=0.f;
    #pragma unroll
    for (int i=0;i<4;i++){ S+=ls[i]; S2+=ls2[i]; }
    ps[c*8+b] = S;
    ps[1024 + c*8+b] = S2;
  }
}

__global__ __launch_bounds__(128) void k_stats2(const float* __restrict__ ps, float* __restrict__ mr){
  int c = threadIdx.x;
  float S=0.f, S2=0.f;
  #pragma unroll
  for (int b=0;b<8;b++){ S += ps[c*8+b]; S2 += ps[1024 + c*8+b]; }
  const float invN = 1.f/(float)(Bb*HW);
  float m = S*invN;
  float var = S2*invN - m*m;
  mr[c]      = m;
  mr[Cc + c] = rsqrtf(var + 1e-5f);
}

__global__ __launch_bounds__(256) void k_apply(float* __restrict__ out, const float* __restrict__ x,
                                               const float* __restrict__ mr, const float* __restrict__ gamma,
                                               const float* __restrict__ beta){
  int i = blockIdx.x*256 + threadIdx.x;
  int c = (i >> 12) & 127;
  float4 v  = ((const float4*)out)[i];
  float4 xi = ((const float4*)x)[i];
  float m = mr[c], r = mr[Cc+c], g = gamma[c], be = beta[c];
  float* vp = (float*)&v; const float* xp = (const float*)&xi;
  float4 o; float* op = (float*)&o;
  #pragma unroll
  for (int j=0;j<4;j++){
    float t = (vp[j]-m)*r*g + be;
    t = t / (1.f + expf(-t));
    op[j] = t + xp[j];
  }
  ((float4*)out)[i] = o;
}

extern "C" void kernel_launch(void* const* d_in, const int* in_sizes, int n_in,
                              void* d_out, int out_size, void* d_ws, size_t ws_size,
                              hipStream_t stream) {
  const float* x     = (const float*)d_in[0];
  const float* w_off = (const float*)d_in[1];
  const float* b_off = (const float*)d_in[2];
  const float* w_dw  = (const float*)d_in[3];
  const float* gamma = (const float*)d_in[4];
  const float* beta  = (const float*)d_in[5];
  float* out = (float*)d_out;

  float* wp2 = (float*)d_ws;                 // 23040
  float* wdt = wp2 + 23040;                  // 1152
  float* mr  = wp2 + 24576;                  // 256
  float* ps  = mr + 256;                     // 2048

  u32* recs = (u32*)(wp2 + 32768);           // NPIX*36 dwords
  u32* xt16 = recs + (size_t)NPIX*36;        // NPIX*64 dwords (bf16x2)

  hipLaunchKernelGGL(k_repack, dim3((Cc*9*20 + 9*Cc + 255)/256), dim3(256), 0, stream, w_off, w_dw, wp2, wdt);
  hipLaunchKernelGGL(k_offset, dim3(512), dim3(256), 0, stream, x, wp2, out);   // partials -> d_out
  hipLaunchKernelGGL(k_tx,     dim3(2048),     dim3(256), 0, stream, x, xt16);
  hipLaunchKernelGGL(k_rec,    dim3(NPIX/256), dim3(256), 0, stream, out, b_off, recs);
  hipLaunchKernelGGL(k_deform_rec, dim3(NPIX/16), dim3(256), 0, stream, xt16, recs, wdt, out);
  hipLaunchKernelGGL(k_stats1, dim3(Cc*Bb), dim3(256), 0, stream, out, ps);
  hipLaunchKernelGGL(k_stats2, dim3(1),     dim3(128), 0, stream, ps, mr);
  hipLaunchKernelGGL(k_apply,  dim3(NPIX*Cc/4/256), dim3(256), 0, stream, out, x, mr, gamma, beta);
}

// Round 8
// 220.500 us; speedup vs baseline: 4.2336x; 1.0032x over previous
//
#include <hip/hip_runtime.h>
#include <hip/hip_fp16.h>
#include <math.h>

#define Cc 128
#define Hh 128
#define Ww 128
#define Bb 8
#define HW 16384
#define NPIX 131072   // B*H*W
#define NOFF 18

typedef unsigned int u32;

static __device__ __forceinline__ u32 f2bf(float f){
  u32 u = __float_as_uint(f);
  return (u + 0x7fffu + ((u >> 16) & 1u)) >> 16;   // RNE
}

// ---------------- K0: repack offset-conv weights [c][k][o(pad20)] + w_dw transpose [k][c] ----------------
__global__ __launch_bounds__(256) void k_repack(const float* __restrict__ w_off, const float* __restrict__ w_dw,
                                                float* __restrict__ wp2, float* __restrict__ wdt){
  int i = blockIdx.x*256 + threadIdx.x;
  if (i < Cc*9*20){
    int o = i % 20; int t = i / 20; int k = t % 9; int c = t / 9;
    wp2[i] = (o < NOFF) ? w_off[(o*Cc + c)*9 + k] : 0.f;
  }
  int j = i - Cc*9*20;
  if (j >= 0 && j < 9*Cc){
    int c = j % Cc; int k = j / Cc;
    wdt[j] = w_dw[c*9 + k];
  }
}

// ---------------- K1: offset conv (Cin=128 -> 18, 3x3, pad 1), 4-way channel split ----------------
// 1024 blocks: [b(8)][rowg(16)][colh(2)][cq(4)]. Block: 256 thr, each 2 pixels.
// Weights in LDS [32ch][9k][20o]. Partials into d_out (scratch).
__global__ __launch_bounds__(256) void k_offset(const float* __restrict__ x, const float* __restrict__ wp2,
                                                float* __restrict__ part){
  __shared__ float wlds[32*9*20];                  // 23040 B
  int tid = threadIdx.x;
  int cq  = blockIdx.x & 3;
  int pb  = blockIdx.x >> 2;
  int colh  = pb & 1;
  int rowg  = (pb >> 1) & 15;
  int b     = pb >> 5;

  {
    const float4* src = (const float4*)(wp2 + cq*5760);
    float4* dst = (float4*)wlds;
    for (int i = tid; i < 1440; i += 256) dst[i] = src[i];
  }
  __syncthreads();

  int lane = tid & 63, wid = tid >> 6;
  int gr0 = rowg*8 + wid*2;
  int col = colh*64 + lane;

  int rb[4]; float rm[4];
  #pragma unroll
  for (int j=0;j<4;j++){
    int gr = gr0 - 1 + j;
    rm[j] = (gr>=0 && gr<Hh) ? 1.f : 0.f;
    rb[j] = min(max(gr,0),Hh-1)*Ww;
  }
  int cx[3]; float cm[3];
  #pragma unroll
  for (int s=0;s<3;s++){
    int cc = col + s - 1;
    cm[s] = (cc>=0 && cc<Ww) ? 1.f : 0.f;
    cx[s] = min(max(cc,0),Ww-1);
  }
  float mk[4][3];
  #pragma unroll
  for (int j=0;j<4;j++)
    #pragma unroll
    for (int s=0;s<3;s++) mk[j][s] = rm[j]*cm[s];

  float acc[NOFF][2];
  #pragma unroll
  for (int o=0;o<NOFF;o++){ acc[o][0]=0.f; acc[o][1]=0.f; }

  const float* xb = x + ((size_t)(b*Cc + cq*32))*HW;
  for (int ci=0; ci<32; ci++){
    const float* xc = xb + (size_t)ci*HW;
    float xv[4][3];
    #pragma unroll
    for (int j=0;j<4;j++)
      #pragma unroll
      for (int s=0;s<3;s++) xv[j][s] = xc[rb[j] + cx[s]] * mk[j][s];

    #pragma unroll
    for (int k=0;k<9;k++){
      const float* wk = &wlds[(ci*9 + k)*20];
      float4 wa = *(const float4*)(wk);
      float4 wb = *(const float4*)(wk+4);
      float4 wc = *(const float4*)(wk+8);
      float4 wd = *(const float4*)(wk+12);
      float2 we = *(const float2*)(wk+16);
      int ky = k/3, kx = k%3;
      float xa = xv[ky][kx], xbv = xv[ky+1][kx];
      acc[0][0]  = fmaf(xa, wa.x, acc[0][0]);   acc[0][1]  = fmaf(xbv, wa.x, acc[0][1]);
      acc[1][0]  = fmaf(xa, wa.y, acc[1][0]);   acc[1][1]  = fmaf(xbv, wa.y, acc[1][1]);
      acc[2][0]  = fmaf(xa, wa.z, acc[2][0]);   acc[2][1]  = fmaf(xbv, wa.z, acc[2][1]);
      acc[3][0]  = fmaf(xa, wa.w, acc[3][0]);   acc[3][1]  = fmaf(xbv, wa.w, acc[3][1]);
      acc[4][0]  = fmaf(xa, wb.x, acc[4][0]);   acc[4][1]  = fmaf(xbv, wb.x, acc[4][1]);
      acc[5][0]  = fmaf(xa, wb.y, acc[5][0]);   acc[5][1]  = fmaf(xbv, wb.y, acc[5][1]);
      acc[6][0]  = fmaf(xa, wb.z, acc[6][0]);   acc[6][1]  = fmaf(xbv, wb.z, acc[6][1]);
      acc[7][0]  = fmaf(xa, wb.w, acc[7][0]);   acc[7][1]  = fmaf(xbv, wb.w, acc[7][1]);
      acc[8][0]  = fmaf(xa, wc.x, acc[8][0]);   acc[8][1]  = fmaf(xbv, wc.x, acc[8][1]);
      acc[9][0]  = fmaf(xa, wc.y, acc[9][0]);   acc[9][1]  = fmaf(xbv, wc.y, acc[9][1]);
      acc[10][0] = fmaf(xa, wc.z, acc[10][0]);  acc[10][1] = fmaf(xbv, wc.z, acc[10][1]);
      acc[11][0] = fmaf(xa, wc.w, acc[11][0]);  acc[11][1] = fmaf(xbv, wc.w, acc[11][1]);
      acc[12][0] = fmaf(xa, wd.x, acc[12][0]);  acc[12][1] = fmaf(xbv, wd.x, acc[12][1]);
      acc[13][0] = fmaf(xa, wd.y, acc[13][0]);  acc[13][1] = fmaf(xbv, wd.y, acc[13][1]);
      acc[14][0] = fmaf(xa, wd.z, acc[14][0]);  acc[14][1] = fmaf(xbv, wd.z, acc[14][1]);
      acc[15][0] = fmaf(xa, wd.w, acc[15][0]);  acc[15][1] = fmaf(xbv, wd.w, acc[15][1]);
      acc[16][0] = fmaf(xa, we.x, acc[16][0]);  acc[16][1] = fmaf(xbv, we.x, acc[16][1]);
      acc[17][0] = fmaf(xa, we.y, acc[17][0]);  acc[17][1] = fmaf(xbv, we.y, acc[17][1]);
    }
  }

  float* pp = part + ((size_t)(cq*Bb + b)*NOFF)*HW + gr0*Ww + col;
  #pragma unroll
  for (int o=0;o<NOFF;o++){
    pp[(size_t)o*HW]       = acc[o][0];
    pp[(size_t)o*HW + Ww]  = acc[o][1];
  }
}

// ---------------- K_tx: transpose x NCHW -> NHWC, bf16-packed (2 ch per u32) ----------------
__global__ __launch_bounds__(256) void k_tx(const float* __restrict__ x, u32* __restrict__ xt16){
  __shared__ float t[128][65];
  int tid = threadIdx.x;
  int b   = blockIdx.x >> 8;
  int hw0 = (blockIdx.x & 255) << 6;
  int lane = tid & 63, wg = tid >> 6;
  const float* xb = x + (size_t)b*Cc*HW;
  #pragma unroll
  for (int k=0;k<32;k++){
    int c = wg + k*4;
    t[c][lane] = xb[(size_t)c*HW + hw0 + lane];
  }
  __syncthreads();
  u32* ob = xt16 + ((size_t)b*HW + hw0)*64;
  int cpair = tid & 63, grp = tid >> 6;
  #pragma unroll
  for (int k=0;k<16;k++){
    int hwl = grp + k*4;
    float lo = t[cpair*2][hwl];
    float hi = t[cpair*2+1][hwl];
    ob[(size_t)hwl*64 + cpair] = f2bf(lo) | (f2bf(hi) << 16);
  }
}

// ---------------- K_rec: combine 4 partials + bias -> per-pixel sample records ----------------
__global__ __launch_bounds__(256) void k_rec(const float* __restrict__ part, const float* __restrict__ b_off,
                                             u32* __restrict__ recs){
  int px = blockIdx.x*256 + threadIdx.x;
  int b = px >> 14, hw = px & 16383;
  int h = hw >> 7, w = hw & 127;
  float v[NOFF];
  #pragma unroll
  for (int o=0;o<NOFF;o++){
    float a0 = part[((size_t)(b)*NOFF + o)*HW + hw];
    float a1 = part[((size_t)(Bb + b)*NOFF + o)*HW + hw];
    float a2 = part[((size_t)(2*Bb + b)*NOFF + o)*HW + hw];
    float a3 = part[((size_t)(3*Bb + b)*NOFF + o)*HW + hw];
    v[o] = (a0 + a1) + (a2 + a3) + b_off[o];
  }
  u32 rec[36];
  #pragma unroll
  for (int kk=0;kk<9;kk++){
    float py = (float)(h + kk/3 - 1) + v[2*kk];
    float qx = (float)(w + kk%3 - 1) + v[2*kk+1];
    float fy = floorf(py), fx = floorf(qx);
    float ty = py - fy, tx = qx - fx;
    int y0 = (int)fy, x0 = (int)fx;
    int y1 = y0+1, x1 = x0+1;
    bool vy0 = (y0>=0)&&(y0<Hh), vy1=(y1>=0)&&(y1<Hh);
    bool vx0 = (x0>=0)&&(x0<Ww), vx1=(x1>=0)&&(x1<Ww);
    u32 yc0 = (u32)(min(max(y0,0),Hh-1)*Ww), yc1 = (u32)(min(max(y1,0),Hh-1)*Ww);
    u32 xc0 = (u32)min(max(x0,0),Ww-1),      xc1 = (u32)min(max(x1,0),Ww-1);
    rec[2*kk]   = (yc0+xc0) | ((yc0+xc1)<<16);
    rec[2*kk+1] = (yc1+xc0) | ((yc1+xc1)<<16);
    float c00 = (vy0&&vx0) ? (1.f-ty)*(1.f-tx) : 0.f;
    float c01 = (vy0&&vx1) ? (1.f-ty)*tx       : 0.f;
    float c10 = (vy1&&vx0) ? ty*(1.f-tx)       : 0.f;
    float c11 = (vy1&&vx1) ? ty*tx             : 0.f;
    __half2 hA = __floats2half2_rn(c00, c01);
    __half2 hB = __floats2half2_rn(c10, c11);
    rec[18+2*kk] = *(u32*)&hA;
    rec[19+2*kk] = *(u32*)&hB;
  }
  uint4* dst = (uint4*)(recs + (size_t)px*36);
  #pragma unroll
  for (int q=0;q<9;q++) dst[q] = *(uint4*)(rec + q*4);
}

// ---------------- K2: deformable depthwise; bf16 NHWC gathers, all-36-loads-in-flight ----------------
__global__ __launch_bounds__(256) void k_deform_rec(const u32* __restrict__ xt, const u32* __restrict__ recs,
                                                    const float* __restrict__ wdt, float* __restrict__ out){
  __shared__ float pivot[16][132];
  int tid = threadIdx.x, lane = tid & 63, wid = tid >> 6;
  int pxb = blockIdx.x * 16;
  int bu = pxb >> 14, hw0 = pxb & 16383;
  int l2 = lane*2;

  float2 wk[9];
  #pragma unroll
  for (int k=0;k<9;k++) wk[k] = *(const float2*)(wdt + k*Cc + l2);

  const u32* xbu = xt + (size_t)bu*HW*64;

  #pragma unroll
  for (int i=0;i<4;i++){
    int pu = __builtin_amdgcn_readfirstlane(pxb + wid*4 + i);
    const u32* rec = recs + (size_t)pu*36;

    u32 q[9][4];
    #pragma unroll
    for (int kk=0;kk<9;kk++){
      u32 dA = rec[2*kk], dB = rec[2*kk+1];
      q[kk][0] = xbu[(size_t)(dA & 0xFFFFu)*64 + lane];
      q[kk][1] = xbu[(size_t)(dA >> 16)   *64 + lane];
      q[kk][2] = xbu[(size_t)(dB & 0xFFFFu)*64 + lane];
      q[kk][3] = xbu[(size_t)(dB >> 16)   *64 + lane];
    }

    float acc0 = 0.f, acc1 = 0.f;
    #pragma unroll
    for (int kk=0;kk<9;kk++){
      u32 uA = rec[18+2*kk], uB = rec[19+2*kk];
      __half2 hA = *(__half2*)&uA, hB = *(__half2*)&uB;
      float c00 = __low2float(hA), c01 = __high2float(hA);
      float c10 = __low2float(hB), c11 = __high2float(hB);
      float v0l = __uint_as_float(q[kk][0] << 16), v0h = __uint_as_float(q[kk][0] & 0xffff0000u);
      float v1l = __uint_as_float(q[kk][1] << 16), v1h = __uint_as_float(q[kk][1] & 0xffff0000u);
      float v2l = __uint_as_float(q[kk][2] << 16), v2h = __uint_as_float(q[kk][2] & 0xffff0000u);
      float v3l = __uint_as_float(q[kk][3] << 16), v3h = __uint_as_float(q[kk][3] & 0xffff0000u);
      float s0 = c00*v0l; s0 = fmaf(c01, v1l, s0); s0 = fmaf(c10, v2l, s0); s0 = fmaf(c11, v3l, s0);
      float s1 = c00*v0h; s1 = fmaf(c01, v1h, s1); s1 = fmaf(c10, v2h, s1); s1 = fmaf(c11, v3h, s1);
      acc0 = fmaf(wk[kk].x, s0, acc0);
      acc1 = fmaf(wk[kk].y, s1, acc1);
    }
    pivot[wid*4+i][l2]   = acc0;
    pivot[wid*4+i][l2+1] = acc1;
  }
  __syncthreads();
  #pragma unroll
  for (int it=0; it<2; it++){
    int c = (tid>>2) + it*64, qd = tid & 3;
    float4 r = make_float4(pivot[qd*4+0][c], pivot[qd*4+1][c], pivot[qd*4+2][c], pivot[qd*4+3][c]);
    *(float4*)(out + ((size_t)bu*Cc + c)*HW + hw0 + qd*4) = r;
  }
}

// ---------------- stats + apply ----------------
__global__ __launch_bounds__(256) void k_stats1(const float* __restrict__ dw, float* __restrict__ ps){
  int c = blockIdx.x >> 3, b = blockIdx.x & 7;
  const float4* p = (const float4*)(dw + ((size_t)b*Cc + c)*HW);
  float s = 0.f, s2 = 0.f;
  for (int i=threadIdx.x; i<HW/4; i+=256){
    float4 v = p[i];
    s += v.x + v.y + v.z + v.w;
    s2 = fmaf(v.x, v.x, s2); s2 = fmaf(v.y, v.y, s2);
    s2 = fmaf(v.z, v.z, s2); s2 = fmaf(v.w, v.w, s2);
  }
  #pragma unroll
  for (int d=32; d>0; d>>=1){ s += __shfl_down(s, d, 64); s2 += __shfl_down(s2, d, 64); }
  __shared__ float ls[4], ls2[4];
  int lane = threadIdx.x & 63, wid = threadIdx.x >> 6;
  if (lane==0){ ls[wid]=s; ls2[wid]=s2; }
  __syncthreads();
  if (threadIdx.x==0){
    float S=0.f, S2=0.f;
    #pragma unroll
    for (int i=0;i<4;i++){ S+=ls[i]; S2+=ls2[i]; }
    ps[c*8+b] = S;
    ps[1024 + c*8+b] = S2;
  }
}

__global__ __launch_bounds__(128) void k_stats2(const float* __restrict__ ps, float* __restrict__ mr){
  int c = threadIdx.x;
  float S=0.f, S2=0.f;
  #pragma unroll
  for (int b=0;b<8;b++){ S += ps[c*8+b]; S2 += ps[1024 + c*8+b]; }
  const float invN = 1.f/(float)(Bb*HW);
  float m = S*invN;
  float var = S2*invN - m*m;
  mr[c]      = m;
  mr[Cc + c] = rsqrtf(var + 1e-5f);
}

__global__ __launch_bounds__(256) void k_apply(float* __restrict__ out, const float* __restrict__ x,
                                               const float* __restrict__ mr, const float* __restrict__ gamma,
                                               const float* __restrict__ beta){
  int i = blockIdx.x*256 + threadIdx.x;
  int c = (i >> 12) & 127;
  float4 v  = ((const float4*)out)[i];
  float4 xi = ((const float4*)x)[i];
  float m = mr[c], r = mr[Cc+c], g = gamma[c], be = beta[c];
  float* vp = (float*)&v; const float* xp = (const float*)&xi;
  float4 o; float* op = (float*)&o;
  #pragma unroll
  for (int j=0;j<4;j++){
    float t = (vp[j]-m)*r*g + be;
    t = t / (1.f + expf(-t));
    op[j] = t + xp[j];
  }
  ((float4*)out)[i] = o;
}

extern "C" void kernel_launch(void* const* d_in, const int* in_sizes, int n_in,
                              void* d_out, int out_size, void* d_ws, size_t ws_size,
                              hipStream_t stream) {
  const float* x     = (const float*)d_in[0];
  const float* w_off = (const float*)d_in[1];
  const float* b_off = (const float*)d_in[2];
  const float* w_dw  = (const float*)d_in[3];
  const float* gamma = (const float*)d_in[4];
  const float* beta  = (const float*)d_in[5];
  float* out = (float*)d_out;

  float* wp2 = (float*)d_ws;                 // 23040
  float* wdt = wp2 + 23040;                  // 1152
  float* mr  = wp2 + 24576;                  // 256
  float* ps  = mr + 256;                     // 2048

  u32* recs = (u32*)(wp2 + 32768);           // NPIX*36 dwords
  u32* xt16 = recs + (size_t)NPIX*36;        // NPIX*64 dwords (bf16x2)

  hipLaunchKernelGGL(k_repack, dim3((Cc*9*20 + 9*Cc + 255)/256), dim3(256), 0, stream, w_off, w_dw, wp2, wdt);
  hipLaunchKernelGGL(k_offset, dim3(1024), dim3(256), 0, stream, x, wp2, out);   // 4 partials -> d_out
  hipLaunchKernelGGL(k_tx,     dim3(2048),     dim3(256), 0, stream, x, xt16);
  hipLaunchKernelGGL(k_rec,    dim3(NPIX/256), dim3(256), 0, stream, out, b_off, recs);
  hipLaunchKernelGGL(k_deform_rec, dim3(NPIX/16), dim3(256), 0, stream, xt16, recs, wdt, out);
  hipLaunchKernelGGL(k_stats1, dim3(Cc*Bb), dim3(256), 0, stream, out, ps);
  hipLaunchKernelGGL(k_stats2, dim3(1),     dim3(128), 0, stream, ps, mr);
  hipLaunchKernelGGL(k_apply,  dim3(NPIX*Cc/4/256), dim3(256), 0, stream, out, x, mr, gamma, beta);
}

// Round 9
// 178.295 us; speedup vs baseline: 5.2358x; 1.2367x over previous
//
#include <hip/hip_runtime.h>
#include <hip/hip_fp16.h>
#include <math.h>

#define Cc 128
#define Hh 128
#define Ww 128
#define Bb 8
#define HW 16384
#define NPIX 131072   // B*H*W
#define NOFF 18

typedef unsigned int u32;
typedef __attribute__((ext_vector_type(8)))  short bf16x8;
typedef __attribute__((ext_vector_type(16))) float f32x16;

static __device__ __forceinline__ u32 f2bf(float f){
  u32 u = __float_as_uint(f);
  return (u + 0x7fffu + ((u >> 16) & 1u)) >> 16;   // RNE
}

// ---------------- K0: pack B-fragments for MFMA offset conv + w_dw transpose [k][c] ----------------
// wBf: [step=tap*8+chunk][lane][4 u32]; lane -> (o = lane&31, half = lane>>5);
// element j (0..7): c = chunk*16 + half*8 + j; value = w_off[o][c][tap] (o<18 else 0), bf16-packed.
__global__ __launch_bounds__(256) void k_repack(const float* __restrict__ w_off, const float* __restrict__ w_dw,
                                                u32* __restrict__ wBf, float* __restrict__ wdt){
  int i = blockIdx.x*256 + threadIdx.x;
  if (i < 72*64*4){
    int step = i >> 8;
    int r    = i & 255;
    int lane = r >> 2;
    int q    = r & 3;
    int tap  = step / 8, chunk = step % 8;
    int o    = lane & 31, half = lane >> 5;
    int c0   = chunk*16 + half*8 + 2*q;
    float v0 = (o < NOFF) ? w_off[(size_t)(o*Cc + c0    )*9 + tap] : 0.f;
    float v1 = (o < NOFF) ? w_off[(size_t)(o*Cc + c0 + 1)*9 + tap] : 0.f;
    wBf[i] = f2bf(v0) | (f2bf(v1) << 16);
  }
  int j = i - 72*64*4;
  if (j >= 0 && j < 9*Cc){
    int c = j % Cc; int k = j / Cc;
    wdt[j] = w_dw[c*9 + k];
  }
}

// ---------------- K_tx: transpose x NCHW -> NHWC, bf16-packed (2 ch per u32) ----------------
__global__ __launch_bounds__(256) void k_tx(const float* __restrict__ x, u32* __restrict__ xt16){
  __shared__ float t[128][65];
  int tid = threadIdx.x;
  int b   = blockIdx.x >> 8;
  int hw0 = (blockIdx.x & 255) << 6;
  int lane = tid & 63, wg = tid >> 6;
  const float* xb = x + (size_t)b*Cc*HW;
  #pragma unroll
  for (int k=0;k<32;k++){
    int c = wg + k*4;
    t[c][lane] = xb[(size_t)c*HW + hw0 + lane];
  }
  __syncthreads();
  u32* ob = xt16 + ((size_t)b*HW + hw0)*64;
  int cpair = tid & 63, grp = tid >> 6;
  #pragma unroll
  for (int k=0;k<16;k++){
    int hwl = grp + k*4;
    float lo = t[cpair*2][hwl];
    float hi = t[cpair*2+1][hwl];
    ob[(size_t)hwl*64 + cpair] = f2bf(lo) | (f2bf(hi) << 16);
  }
}

// ---------------- K1: offset conv via MFMA + fused record build ----------------
// grid 1024 = [b(8)][h(128)]; block 256 = 4 waves; wave = 32-px tile (M=32, N=32 (18 used), K=1152).
__global__ __launch_bounds__(256) void k_offset_mfma(const u32* __restrict__ xt, const u32* __restrict__ wBf,
                                                     const float* __restrict__ b_off, u32* __restrict__ recs){
  __shared__ float piv[128][21];
  int tid = threadIdx.x, lane = tid & 63, wid = tid >> 6;
  int b = blockIdx.x >> 7, h = blockIdx.x & 127;
  int row = lane & 31, half = lane >> 5;
  int w0 = wid*32;
  int w = w0 + row;

  const u32* xb = xt + (size_t)b*HW*64;

  int taddr[9]; bool tval[9];
  #pragma unroll
  for (int t=0;t<9;t++){
    int ky = t/3 - 1, kx = t%3 - 1;
    int hh = h + ky, wt = w + kx;
    bool v = (hh>=0)&&(hh<Hh)&&(wt>=0)&&(wt<Ww);
    int hwd = hh*Ww + wt;
    hwd = min(max(hwd,0),HW-1);
    taddr[t] = hwd*64 + half*4;      // dword offset into xt (16B aligned)
    tval[t] = v;
  }

  f32x16 acc;
  #pragma unroll
  for (int i=0;i<16;i++) acc[i] = 0.f;

  const uint4* wb = (const uint4*)wBf;
  #pragma unroll 1
  for (int t=0;t<9;t++){
    const uint4* ap = (const uint4*)(xb + taddr[t]);
    bool v = tval[t];
    #pragma unroll
    for (int ch=0;ch<8;ch++){
      uint4 a = ap[ch*2];                 // 16 channels = 8 u32; half-lane picks 4
      if (!v){ a.x=0u; a.y=0u; a.z=0u; a.w=0u; }
      uint4 bf = wb[(t*8+ch)*64 + lane];
      acc = __builtin_amdgcn_mfma_f32_32x32x16_bf16(*(bf16x8*)&a, *(bf16x8*)&bf, acc, 0, 0, 0);
    }
  }

  // pivot acc -> LDS [px 0..127][o 0..17]
  int o = lane & 31;
  #pragma unroll
  for (int r=0;r<16;r++){
    int pxl = w0 + ((r&3) + 8*(r>>2) + 4*half);
    if (o < NOFF) piv[pxl][o] = acc[r];
  }
  __syncthreads();

  // fused record build: thread t<128 handles pixel w=t of this row
  if (tid < 128){
    int wpx = tid;
    float v[NOFF];
    #pragma unroll
    for (int oo=0;oo<NOFF;oo++) v[oo] = piv[wpx][oo] + b_off[oo];

    u32 rec[36];
    #pragma unroll
    for (int kk=0;kk<9;kk++){
      float py = (float)(h + kk/3 - 1) + v[2*kk];
      float qx = (float)(wpx + kk%3 - 1) + v[2*kk+1];
      float fy = floorf(py), fx = floorf(qx);
      float ty = py - fy, tx = qx - fx;
      int y0 = (int)fy, x0 = (int)fx;
      int y1 = y0+1, x1 = x0+1;
      bool vy0 = (y0>=0)&&(y0<Hh), vy1=(y1>=0)&&(y1<Hh);
      bool vx0 = (x0>=0)&&(x0<Ww), vx1=(x1>=0)&&(x1<Ww);
      u32 yc0 = (u32)(min(max(y0,0),Hh-1)*Ww), yc1 = (u32)(min(max(y1,0),Hh-1)*Ww);
      u32 xc0 = (u32)min(max(x0,0),Ww-1),      xc1 = (u32)min(max(x1,0),Ww-1);
      rec[2*kk]   = (yc0+xc0) | ((yc0+xc1)<<16);
      rec[2*kk+1] = (yc1+xc0) | ((yc1+xc1)<<16);
      float c00 = (vy0&&vx0) ? (1.f-ty)*(1.f-tx) : 0.f;
      float c01 = (vy0&&vx1) ? (1.f-ty)*tx       : 0.f;
      float c10 = (vy1&&vx0) ? ty*(1.f-tx)       : 0.f;
      float c11 = (vy1&&vx1) ? ty*tx             : 0.f;
      __half2 hA = __floats2half2_rn(c00, c01);
      __half2 hB = __floats2half2_rn(c10, c11);
      rec[18+2*kk] = *(u32*)&hA;
      rec[19+2*kk] = *(u32*)&hB;
    }
    int pxg = blockIdx.x*128 + wpx;
    uint4* dst = (uint4*)(recs + (size_t)pxg*36);
    #pragma unroll
    for (int q=0;q<9;q++) dst[q] = *(uint4*)(rec + q*4);
  }
}

// ---------------- K2: deformable depthwise; bf16 NHWC gathers, all-36-loads-in-flight ----------------
__global__ __launch_bounds__(256) void k_deform_rec(const u32* __restrict__ xt, const u32* __restrict__ recs,
                                                    const float* __restrict__ wdt, float* __restrict__ out){
  __shared__ float pivot[16][132];
  int tid = threadIdx.x, lane = tid & 63, wid = tid >> 6;
  int pxb = blockIdx.x * 16;
  int bu = pxb >> 14, hw0 = pxb & 16383;
  int l2 = lane*2;

  float2 wk[9];
  #pragma unroll
  for (int k=0;k<9;k++) wk[k] = *(const float2*)(wdt + k*Cc + l2);

  const u32* xbu = xt + (size_t)bu*HW*64;

  #pragma unroll
  for (int i=0;i<4;i++){
    int pu = __builtin_amdgcn_readfirstlane(pxb + wid*4 + i);
    const u32* rec = recs + (size_t)pu*36;

    u32 q[9][4];
    #pragma unroll
    for (int kk=0;kk<9;kk++){
      u32 dA = rec[2*kk], dB = rec[2*kk+1];
      q[kk][0] = xbu[(size_t)(dA & 0xFFFFu)*64 + lane];
      q[kk][1] = xbu[(size_t)(dA >> 16)   *64 + lane];
      q[kk][2] = xbu[(size_t)(dB & 0xFFFFu)*64 + lane];
      q[kk][3] = xbu[(size_t)(dB >> 16)   *64 + lane];
    }

    float acc0 = 0.f, acc1 = 0.f;
    #pragma unroll
    for (int kk=0;kk<9;kk++){
      u32 uA = rec[18+2*kk], uB = rec[19+2*kk];
      __half2 hA = *(__half2*)&uA, hB = *(__half2*)&uB;
      float c00 = __low2float(hA), c01 = __high2float(hA);
      float c10 = __low2float(hB), c11 = __high2float(hB);
      float v0l = __uint_as_float(q[kk][0] << 16), v0h = __uint_as_float(q[kk][0] & 0xffff0000u);
      float v1l = __uint_as_float(q[kk][1] << 16), v1h = __uint_as_float(q[kk][1] & 0xffff0000u);
      float v2l = __uint_as_float(q[kk][2] << 16), v2h = __uint_as_float(q[kk][2] & 0xffff0000u);
      float v3l = __uint_as_float(q[kk][3] << 16), v3h = __uint_as_float(q[kk][3] & 0xffff0000u);
      float s0 = c00*v0l; s0 = fmaf(c01, v1l, s0); s0 = fmaf(c10, v2l, s0); s0 = fmaf(c11, v3l, s0);
      float s1 = c00*v0h; s1 = fmaf(c01, v1h, s1); s1 = fmaf(c10, v2h, s1); s1 = fmaf(c11, v3h, s1);
      acc0 = fmaf(wk[kk].x, s0, acc0);
      acc1 = fmaf(wk[kk].y, s1, acc1);
    }
    pivot[wid*4+i][l2]   = acc0;
    pivot[wid*4+i][l2+1] = acc1;
  }
  __syncthreads();
  #pragma unroll
  for (int it=0; it<2; it++){
    int c = (tid>>2) + it*64, qd = tid & 3;
    float4 r = make_float4(pivot[qd*4+0][c], pivot[qd*4+1][c], pivot[qd*4+2][c], pivot[qd*4+3][c]);
    *(float4*)(out + ((size_t)bu*Cc + c)*HW + hw0 + qd*4) = r;
  }
}

// ---------------- stats + apply ----------------
__global__ __launch_bounds__(256) void k_stats1(const float* __restrict__ dw, float* __restrict__ ps){
  int c = blockIdx.x >> 3, b = blockIdx.x & 7;
  const float4* p = (const float4*)(dw + ((size_t)b*Cc + c)*HW);
  float s = 0.f, s2 = 0.f;
  for (int i=threadIdx.x; i<HW/4; i+=256){
    float4 v = p[i];
    s += v.x + v.y + v.z + v.w;
    s2 = fmaf(v.x, v.x, s2); s2 = fmaf(v.y, v.y, s2);
    s2 = fmaf(v.z, v.z, s2); s2 = fmaf(v.w, v.w, s2);
  }
  #pragma unroll
  for (int d=32; d>0; d>>=1){ s += __shfl_down(s, d, 64); s2 += __shfl_down(s2, d, 64); }
  __shared__ float ls[4], ls2[4];
  int lane = threadIdx.x & 63, wid = threadIdx.x >> 6;
  if (lane==0){ ls[wid]=s; ls2[wid]=s2; }
  __syncthreads();
  if (threadIdx.x==0){
    float S=0.f, S2=0.f;
    #pragma unroll
    for (int i=0;i<4;i++){ S+=ls[i]; S2+=ls2[i]; }
    ps[c*8+b] = S;
    ps[1024 + c*8+b] = S2;
  }
}

__global__ __launch_bounds__(128) void k_stats2(const float* __restrict__ ps, float* __restrict__ mr){
  int c = threadIdx.x;
  float S=0.f, S2=0.f;
  #pragma unroll
  for (int b=0;b<8;b++){ S += ps[c*8+b]; S2 += ps[1024 + c*8+b]; }
  const float invN = 1.f/(float)(Bb*HW);
  float m = S*invN;
  float var = S2*invN - m*m;
  mr[c]      = m;
  mr[Cc + c] = rsqrtf(var + 1e-5f);
}

__global__ __launch_bounds__(256) void k_apply(float* __restrict__ out, const float* __restrict__ x,
                                               const float* __restrict__ mr, const float* __restrict__ gamma,
                                               const float* __restrict__ beta){
  int i = blockIdx.x*256 + threadIdx.x;
  int c = (i >> 12) & 127;
  float4 v  = ((const float4*)out)[i];
  float4 xi = ((const float4*)x)[i];
  float m = mr[c], r = mr[Cc+c], g = gamma[c], be = beta[c];
  float* vp = (float*)&v; const float* xp = (const float*)&xi;
  float4 o; float* op = (float*)&o;
  #pragma unroll
  for (int j=0;j<4;j++){
    float t = (vp[j]-m)*r*g + be;
    t = t / (1.f + expf(-t));
    op[j] = t + xp[j];
  }
  ((float4*)out)[i] = o;
}

extern "C" void kernel_launch(void* const* d_in, const int* in_sizes, int n_in,
                              void* d_out, int out_size, void* d_ws, size_t ws_size,
                              hipStream_t stream) {
  const float* x     = (const float*)d_in[0];
  const float* w_off = (const float*)d_in[1];
  const float* b_off = (const float*)d_in[2];
  const float* w_dw  = (const float*)d_in[3];
  const float* gamma = (const float*)d_in[4];
  const float* beta  = (const float*)d_in[5];
  float* out = (float*)d_out;

  // ws layout (same proven footprint as R6-R8):
  u32*   wBf = (u32*)d_ws;                   // 18432 u32 (73.7 KB) in old wp2 slot
  float* wdt = (float*)d_ws + 23040;         // 1152
  float* mr  = (float*)d_ws + 24576;         // 256
  float* ps  = mr + 256;                     // 2048
  u32* recs  = (u32*)d_ws + 32768;           // NPIX*36 dwords
  u32* xt16  = recs + (size_t)NPIX*36;       // NPIX*64 dwords (bf16x2)

  hipLaunchKernelGGL(k_repack, dim3((72*64*4 + 9*Cc + 255)/256), dim3(256), 0, stream, w_off, w_dw, wBf, wdt);
  hipLaunchKernelGGL(k_tx,     dim3(2048), dim3(256), 0, stream, x, xt16);
  hipLaunchKernelGGL(k_offset_mfma, dim3(1024), dim3(256), 0, stream, xt16, wBf, b_off, recs);
  hipLaunchKernelGGL(k_deform_rec,  dim3(NPIX/16), dim3(256), 0, stream, xt16, recs, wdt, out);
  hipLaunchKernelGGL(k_stats1, dim3(Cc*Bb), dim3(256), 0, stream, out, ps);
  hipLaunchKernelGGL(k_stats2, dim3(1),     dim3(128), 0, stream, ps, mr);
  hipLaunchKernelGGL(k_apply,  dim3(NPIX*Cc/4/256), dim3(256), 0, stream, out, x, mr, gamma, beta);
}

// Round 10
// 171.084 us; speedup vs baseline: 5.4564x; 1.0421x over previous
//
#include <hip/hip_runtime.h>
#include <hip/hip_fp16.h>
#include <math.h>

#define Cc 128
#define Hh 128
#define Ww 128
#define Bb 8
#define HW 16384
#define NPIX 131072   // B*H*W
#define NOFF 18

typedef unsigned int u32;
typedef __attribute__((ext_vector_type(8)))  short bf16x8;
typedef __attribute__((ext_vector_type(16))) float f32x16;

static __device__ __forceinline__ u32 f2bf(float f){
  u32 u = __float_as_uint(f);
  return (u + 0x7fffu + ((u >> 16) & 1u)) >> 16;   // RNE
}

// ---------------- K0: pack B-fragments for MFMA offset conv + w_dw transpose [k][c] ----------------
__global__ __launch_bounds__(256) void k_repack(const float* __restrict__ w_off, const float* __restrict__ w_dw,
                                                u32* __restrict__ wBf, float* __restrict__ wdt){
  int i = blockIdx.x*256 + threadIdx.x;
  if (i < 72*64*4){
    int step = i >> 8;
    int r    = i & 255;
    int lane = r >> 2;
    int q    = r & 3;
    int tap  = step / 8, chunk = step % 8;
    int o    = lane & 31, half = lane >> 5;
    int c0   = chunk*16 + half*8 + 2*q;
    float v0 = (o < NOFF) ? w_off[(size_t)(o*Cc + c0    )*9 + tap] : 0.f;
    float v1 = (o < NOFF) ? w_off[(size_t)(o*Cc + c0 + 1)*9 + tap] : 0.f;
    wBf[i] = f2bf(v0) | (f2bf(v1) << 16);
  }
  int j = i - 72*64*4;
  if (j >= 0 && j < 9*Cc){
    int c = j % Cc; int k = j / Cc;
    wdt[j] = w_dw[c*9 + k];
  }
}

// ---------------- K_tx: transpose x NCHW -> NHWC, bf16-packed (2 ch per u32) ----------------
__global__ __launch_bounds__(256) void k_tx(const float* __restrict__ x, u32* __restrict__ xt16){
  __shared__ float t[128][65];
  int tid = threadIdx.x;
  int b   = blockIdx.x >> 8;
  int hw0 = (blockIdx.x & 255) << 6;
  int lane = tid & 63, wg = tid >> 6;
  const float* xb = x + (size_t)b*Cc*HW;
  #pragma unroll
  for (int k=0;k<32;k++){
    int c = wg + k*4;
    t[c][lane] = xb[(size_t)c*HW + hw0 + lane];
  }
  __syncthreads();
  u32* ob = xt16 + ((size_t)b*HW + hw0)*64;
  int cpair = tid & 63, grp = tid >> 6;
  #pragma unroll
  for (int k=0;k<16;k++){
    int hwl = grp + k*4;
    float lo = t[cpair*2][hwl];
    float hi = t[cpair*2+1][hwl];
    ob[(size_t)hwl*64 + cpair] = f2bf(lo) | (f2bf(hi) << 16);
  }
}

// ---------------- K1: offset conv via MFMA + fused record build ----------------
__global__ __launch_bounds__(256) void k_offset_mfma(const u32* __restrict__ xt, const u32* __restrict__ wBf,
                                                     const float* __restrict__ b_off, u32* __restrict__ recs){
  __shared__ float piv[128][21];
  int tid = threadIdx.x, lane = tid & 63, wid = tid >> 6;
  int b = blockIdx.x >> 7, h = blockIdx.x & 127;
  int row = lane & 31, half = lane >> 5;
  int w0 = wid*32;
  int w = w0 + row;

  const u32* xb = xt + (size_t)b*HW*64;

  int taddr[9]; bool tval[9];
  #pragma unroll
  for (int t=0;t<9;t++){
    int ky = t/3 - 1, kx = t%3 - 1;
    int hh = h + ky, wt = w + kx;
    bool v = (hh>=0)&&(hh<Hh)&&(wt>=0)&&(wt<Ww);
    int hwd = hh*Ww + wt;
    hwd = min(max(hwd,0),HW-1);
    taddr[t] = hwd*64 + half*4;
    tval[t] = v;
  }

  f32x16 acc;
  #pragma unroll
  for (int i=0;i<16;i++) acc[i] = 0.f;

  const uint4* wb = (const uint4*)wBf;
  #pragma unroll 1
  for (int t=0;t<9;t++){
    const uint4* ap = (const uint4*)(xb + taddr[t]);
    bool v = tval[t];
    #pragma unroll
    for (int ch=0;ch<8;ch++){
      uint4 a = ap[ch*2];
      if (!v){ a.x=0u; a.y=0u; a.z=0u; a.w=0u; }
      uint4 bf = wb[(t*8+ch)*64 + lane];
      acc = __builtin_amdgcn_mfma_f32_32x32x16_bf16(*(bf16x8*)&a, *(bf16x8*)&bf, acc, 0, 0, 0);
    }
  }

  int o = lane & 31;
  #pragma unroll
  for (int r=0;r<16;r++){
    int pxl = w0 + ((r&3) + 8*(r>>2) + 4*half);
    if (o < NOFF) piv[pxl][o] = acc[r];
  }
  __syncthreads();

  if (tid < 128){
    int wpx = tid;
    float v[NOFF];
    #pragma unroll
    for (int oo=0;oo<NOFF;oo++) v[oo] = piv[wpx][oo] + b_off[oo];

    u32 rec[36];
    #pragma unroll
    for (int kk=0;kk<9;kk++){
      float py = (float)(h + kk/3 - 1) + v[2*kk];
      float qx = (float)(wpx + kk%3 - 1) + v[2*kk+1];
      float fy = floorf(py), fx = floorf(qx);
      float ty = py - fy, tx = qx - fx;
      int y0 = (int)fy, x0 = (int)fx;
      int y1 = y0+1, x1 = x0+1;
      bool vy0 = (y0>=0)&&(y0<Hh), vy1=(y1>=0)&&(y1<Hh);
      bool vx0 = (x0>=0)&&(x0<Ww), vx1=(x1>=0)&&(x1<Ww);
      u32 yc0 = (u32)(min(max(y0,0),Hh-1)*Ww), yc1 = (u32)(min(max(y1,0),Hh-1)*Ww);
      u32 xc0 = (u32)min(max(x0,0),Ww-1),      xc1 = (u32)min(max(x1,0),Ww-1);
      rec[2*kk]   = (yc0+xc0) | ((yc0+xc1)<<16);
      rec[2*kk+1] = (yc1+xc0) | ((yc1+xc1)<<16);
      float c00 = (vy0&&vx0) ? (1.f-ty)*(1.f-tx) : 0.f;
      float c01 = (vy0&&vx1) ? (1.f-ty)*tx       : 0.f;
      float c10 = (vy1&&vx0) ? ty*(1.f-tx)       : 0.f;
      float c11 = (vy1&&vx1) ? ty*tx             : 0.f;
      __half2 hA = __floats2half2_rn(c00, c01);
      __half2 hB = __floats2half2_rn(c10, c11);
      rec[18+2*kk] = *(u32*)&hA;
      rec[19+2*kk] = *(u32*)&hB;
    }
    int pxg = blockIdx.x*128 + wpx;
    uint4* dst = (uint4*)(recs + (size_t)pxg*36);
    #pragma unroll
    for (int q=0;q<9;q++) dst[q] = *(uint4*)(rec + q*4);
  }
}

// ---------------- K2: deformable depthwise + fused per-block channel stats ----------------
// BF16OUT=1: write bf16-packed dwb; else fp32 out. Both: per-block sum/sumsq partials -> bps.
template<bool BF16OUT>
__global__ __launch_bounds__(256) void k_deform_rec(const u32* __restrict__ xt, const u32* __restrict__ recs,
                                                    const float* __restrict__ wdt, float* __restrict__ out,
                                                    u32* __restrict__ dwb, float* __restrict__ bps){
  __shared__ float pivot[16][132];
  int tid = threadIdx.x, lane = tid & 63, wid = tid >> 6;
  int pxb = blockIdx.x * 16;
  int bu = pxb >> 14, hw0 = pxb & 16383;
  int l2 = lane*2;

  float2 wk[9];
  #pragma unroll
  for (int k=0;k<9;k++) wk[k] = *(const float2*)(wdt + k*Cc + l2);

  const u32* xbu = xt + (size_t)bu*HW*64;

  #pragma unroll
  for (int i=0;i<4;i++){
    int pu = __builtin_amdgcn_readfirstlane(pxb + wid*4 + i);
    const u32* rec = recs + (size_t)pu*36;

    u32 q[9][4];
    #pragma unroll
    for (int kk=0;kk<9;kk++){
      u32 dA = rec[2*kk], dB = rec[2*kk+1];
      q[kk][0] = xbu[(size_t)(dA & 0xFFFFu)*64 + lane];
      q[kk][1] = xbu[(size_t)(dA >> 16)   *64 + lane];
      q[kk][2] = xbu[(size_t)(dB & 0xFFFFu)*64 + lane];
      q[kk][3] = xbu[(size_t)(dB >> 16)   *64 + lane];
    }

    float acc0 = 0.f, acc1 = 0.f;
    #pragma unroll
    for (int kk=0;kk<9;kk++){
      u32 uA = rec[18+2*kk], uB = rec[19+2*kk];
      __half2 hA = *(__half2*)&uA, hB = *(__half2*)&uB;
      float c00 = __low2float(hA), c01 = __high2float(hA);
      float c10 = __low2float(hB), c11 = __high2float(hB);
      float v0l = __uint_as_float(q[kk][0] << 16), v0h = __uint_as_float(q[kk][0] & 0xffff0000u);
      float v1l = __uint_as_float(q[kk][1] << 16), v1h = __uint_as_float(q[kk][1] & 0xffff0000u);
      float v2l = __uint_as_float(q[kk][2] << 16), v2h = __uint_as_float(q[kk][2] & 0xffff0000u);
      float v3l = __uint_as_float(q[kk][3] << 16), v3h = __uint_as_float(q[kk][3] & 0xffff0000u);
      float s0 = c00*v0l; s0 = fmaf(c01, v1l, s0); s0 = fmaf(c10, v2l, s0); s0 = fmaf(c11, v3l, s0);
      float s1 = c00*v0h; s1 = fmaf(c01, v1h, s1); s1 = fmaf(c10, v2h, s1); s1 = fmaf(c11, v3h, s1);
      acc0 = fmaf(wk[kk].x, s0, acc0);
      acc1 = fmaf(wk[kk].y, s1, acc1);
    }
    pivot[wid*4+i][l2]   = acc0;
    pivot[wid*4+i][l2+1] = acc1;
  }
  __syncthreads();
  #pragma unroll
  for (int it=0; it<2; it++){
    int c = (tid>>2) + it*64, qd = tid & 3;
    float4 r = make_float4(pivot[qd*4+0][c], pivot[qd*4+1][c], pivot[qd*4+2][c], pivot[qd*4+3][c]);
    // fused stats partials
    float s  = (r.x + r.y) + (r.z + r.w);
    float s2 = fmaf(r.x,r.x, fmaf(r.y,r.y, fmaf(r.z,r.z, r.w*r.w)));
    s  += __shfl_down(s, 2, 4);  s  += __shfl_down(s, 1, 4);
    s2 += __shfl_down(s2, 2, 4); s2 += __shfl_down(s2, 1, 4);
    if (qd == 0){
      bps[(size_t)blockIdx.x*256 + c]       = s;
      bps[(size_t)blockIdx.x*256 + 128 + c] = s2;
    }
    if (BF16OUT){
      u32 p0 = f2bf(r.x) | (f2bf(r.y) << 16);
      u32 p1 = f2bf(r.z) | (f2bf(r.w) << 16);
      uint2 pp; pp.x = p0; pp.y = p1;
      *(uint2*)&dwb[(((size_t)bu*Cc + c)*HW + hw0)/2 + qd*2] = pp;
    } else {
      *(float4*)(out + ((size_t)bu*Cc + c)*HW + hw0 + qd*4) = r;
    }
  }
}

// ---------------- stats reduce: 8192-block partials -> 128 row partials -> mean/rstd ----------------
__global__ __launch_bounds__(256) void k_statsr1(const float* __restrict__ bps, float* __restrict__ part2){
  int tid = threadIdx.x;
  size_t base = (size_t)blockIdx.x * 64;
  float a = 0.f;
  for (int r=0;r<64;r++) a += bps[(base + r)*256 + tid];
  part2[blockIdx.x*256 + tid] = a;
}

__global__ __launch_bounds__(256) void k_statsr2(const float* __restrict__ part2, float* __restrict__ mr){
  __shared__ float t[256];
  int tid = threadIdx.x;
  float a = 0.f;
  for (int r=0;r<128;r++) a += part2[r*256 + tid];
  t[tid] = a;
  __syncthreads();
  if (tid < 128){
    float S = t[tid], S2 = t[128 + tid];
    const float invN = 1.f/(float)(Bb*HW);
    float m = S*invN;
    float var = S2*invN - m*m;
    mr[tid]       = m;
    mr[Cc + tid]  = rsqrtf(var + 1e-5f);
  }
}

// ---------------- apply: BN + SiLU + residual ----------------
__global__ __launch_bounds__(256) void k_apply_f32(float* __restrict__ out, const float* __restrict__ x,
                                                   const float* __restrict__ mr, const float* __restrict__ gamma,
                                                   const float* __restrict__ beta){
  int i = blockIdx.x*256 + threadIdx.x;
  int c = (i >> 12) & 127;
  float4 v  = ((const float4*)out)[i];
  float4 xi = ((const float4*)x)[i];
  float m = mr[c], r = mr[Cc+c], g = gamma[c], be = beta[c];
  float* vp = (float*)&v; const float* xp = (const float*)&xi;
  float4 o; float* op = (float*)&o;
  #pragma unroll
  for (int j=0;j<4;j++){
    float t = (vp[j]-m)*r*g + be;
    t = t / (1.f + expf(-t));
    op[j] = t + xp[j];
  }
  ((float4*)out)[i] = o;
}

__global__ __launch_bounds__(256) void k_apply_bf16(const u32* __restrict__ dwb, float* __restrict__ out,
                                                    const float* __restrict__ x, const float* __restrict__ mr,
                                                    const float* __restrict__ gamma, const float* __restrict__ beta){
  int i = blockIdx.x*256 + threadIdx.x;
  int c = (i >> 12) & 127;
  uint2 dw = ((const uint2*)dwb)[i];
  float4 xi = ((const float4*)x)[i];
  float m = mr[c], r = mr[Cc+c], g = gamma[c], be = beta[c];
  float v[4];
  v[0] = __uint_as_float(dw.x << 16);
  v[1] = __uint_as_float(dw.x & 0xffff0000u);
  v[2] = __uint_as_float(dw.y << 16);
  v[3] = __uint_as_float(dw.y & 0xffff0000u);
  const float* xp = (const float*)&xi;
  float4 o; float* op = (float*)&o;
  #pragma unroll
  for (int j=0;j<4;j++){
    float t = (v[j]-m)*r*g + be;
    t = t / (1.f + expf(-t));
    op[j] = t + xp[j];
  }
  ((float4*)out)[i] = o;
}

extern "C" void kernel_launch(void* const* d_in, const int* in_sizes, int n_in,
                              void* d_out, int out_size, void* d_ws, size_t ws_size,
                              hipStream_t stream) {
  const float* x     = (const float*)d_in[0];
  const float* w_off = (const float*)d_in[1];
  const float* b_off = (const float*)d_in[2];
  const float* w_dw  = (const float*)d_in[3];
  const float* gamma = (const float*)d_in[4];
  const float* beta  = (const float*)d_in[5];
  float* out = (float*)d_out;

  // ws layout (dword offsets)
  u32*   wBf  = (u32*)d_ws;                            // 18432
  float* wdt  = (float*)d_ws + 23040;                  // 1152
  float* mr   = (float*)d_ws + 24576;                  // 256
  u32*   recs = (u32*)d_ws + 32768;                    // NPIX*36
  u32*   xt16 = recs + (size_t)NPIX*36;                // NPIX*64
  float* bps  = (float*)(xt16 + (size_t)NPIX*64);      // 8192*256
  float* part2= bps + (size_t)8192*256;                // 128*256
  u32*   dwb  = (u32*)(part2 + 128*256);               // NPIX*64 (bf16 out_dw), big path only

  const size_t NEED_B = ((size_t)32768 + (size_t)NPIX*36 + (size_t)NPIX*64
                         + (size_t)8192*256 + 128*256 + (size_t)NPIX*64) * 4;
  bool big = (ws_size >= NEED_B);

  hipLaunchKernelGGL(k_repack, dim3((72*64*4 + 9*Cc + 255)/256), dim3(256), 0, stream, w_off, w_dw, wBf, wdt);
  hipLaunchKernelGGL(k_tx,     dim3(2048), dim3(256), 0, stream, x, xt16);
  hipLaunchKernelGGL(k_offset_mfma, dim3(1024), dim3(256), 0, stream, xt16, wBf, b_off, recs);

  if (big){
    hipLaunchKernelGGL((k_deform_rec<true>), dim3(NPIX/16), dim3(256), 0, stream, xt16, recs, wdt, out, dwb, bps);
  } else {
    hipLaunchKernelGGL((k_deform_rec<false>), dim3(NPIX/16), dim3(256), 0, stream, xt16, recs, wdt, out, dwb, bps);
  }
  hipLaunchKernelGGL(k_statsr1, dim3(128), dim3(256), 0, stream, bps, part2);
  hipLaunchKernelGGL(k_statsr2, dim3(1),   dim3(256), 0, stream, part2, mr);
  if (big){
    hipLaunchKernelGGL(k_apply_bf16, dim3(NPIX*Cc/4/256), dim3(256), 0, stream, dwb, out, x, mr, gamma, beta);
  } else {
    hipLaunchKernelGGL(k_apply_f32,  dim3(NPIX*Cc/4/256), dim3(256), 0, stream, out, x, mr, gamma, beta);
  }
}

// Round 11
// 169.742 us; speedup vs baseline: 5.4996x; 1.0079x over previous
//
#include <hip/hip_runtime.h>
#include <hip/hip_fp16.h>
#include <math.h>

#define Cc 128
#define Hh 128
#define Ww 128
#define Bb 8
#define HW 16384
#define NPIX 131072   // B*H*W
#define NOFF 18

typedef unsigned int u32;
typedef _Float16 half8 __attribute__((ext_vector_type(8)));
typedef __attribute__((ext_vector_type(16))) float f32x16;

static __device__ __forceinline__ u32 pack2h(float a, float b){
  __half2 h = __floats2half2_rn(a, b);
  return *(u32*)&h;
}

// ---------------- K0: pack B-fragments (f16) for MFMA offset conv + w_dw transpose [k][c] ----------------
__global__ __launch_bounds__(256) void k_repack(const float* __restrict__ w_off, const float* __restrict__ w_dw,
                                                u32* __restrict__ wBf, float* __restrict__ wdt){
  int i = blockIdx.x*256 + threadIdx.x;
  if (i < 72*64*4){
    int step = i >> 8;
    int r    = i & 255;
    int lane = r >> 2;
    int q    = r & 3;
    int tap  = step / 8, chunk = step % 8;
    int o    = lane & 31, half = lane >> 5;
    int c0   = chunk*16 + half*8 + 2*q;
    float v0 = (o < NOFF) ? w_off[(size_t)(o*Cc + c0    )*9 + tap] : 0.f;
    float v1 = (o < NOFF) ? w_off[(size_t)(o*Cc + c0 + 1)*9 + tap] : 0.f;
    wBf[i] = pack2h(v0, v1);
  }
  int j = i - 72*64*4;
  if (j >= 0 && j < 9*Cc){
    int c = j % Cc; int k = j / Cc;
    wdt[j] = w_dw[c*9 + k];
  }
}

// ---------------- K_tx: transpose x NCHW -> NHWC, f16-packed (2 ch per u32) ----------------
__global__ __launch_bounds__(256) void k_tx(const float* __restrict__ x, u32* __restrict__ xt16){
  __shared__ float t[128][65];
  int tid = threadIdx.x;
  int b   = blockIdx.x >> 8;
  int hw0 = (blockIdx.x & 255) << 6;
  int lane = tid & 63, wg = tid >> 6;
  const float* xb = x + (size_t)b*Cc*HW;
  #pragma unroll
  for (int k=0;k<32;k++){
    int c = wg + k*4;
    t[c][lane] = xb[(size_t)c*HW + hw0 + lane];
  }
  __syncthreads();
  u32* ob = xt16 + ((size_t)b*HW + hw0)*64;
  int cpair = tid & 63, grp = tid >> 6;
  #pragma unroll
  for (int k=0;k<16;k++){
    int hwl = grp + k*4;
    ob[(size_t)hwl*64 + cpair] = pack2h(t[cpair*2][hwl], t[cpair*2+1][hwl]);
  }
}

// ---------------- K1: offset conv via f16 MFMA + fused record build ----------------
__global__ __launch_bounds__(256) void k_offset_mfma(const u32* __restrict__ xt, const u32* __restrict__ wBf,
                                                     const float* __restrict__ b_off, u32* __restrict__ recs){
  __shared__ float piv[128][21];
  int tid = threadIdx.x, lane = tid & 63, wid = tid >> 6;
  int b = blockIdx.x >> 7, h = blockIdx.x & 127;
  int row = lane & 31, half = lane >> 5;
  int w0 = wid*32;
  int w = w0 + row;

  const u32* xb = xt + (size_t)b*HW*64;

  int taddr[9]; bool tval[9];
  #pragma unroll
  for (int t=0;t<9;t++){
    int ky = t/3 - 1, kx = t%3 - 1;
    int hh = h + ky, wt = w + kx;
    bool v = (hh>=0)&&(hh<Hh)&&(wt>=0)&&(wt<Ww);
    int hwd = hh*Ww + wt;
    hwd = min(max(hwd,0),HW-1);
    taddr[t] = hwd*64 + half*4;
    tval[t] = v;
  }

  f32x16 acc;
  #pragma unroll
  for (int i=0;i<16;i++) acc[i] = 0.f;

  const uint4* wb = (const uint4*)wBf;
  #pragma unroll 1
  for (int t=0;t<9;t++){
    const uint4* ap = (const uint4*)(xb + taddr[t]);
    bool v = tval[t];
    #pragma unroll
    for (int ch=0;ch<8;ch++){
      uint4 a = ap[ch*2];
      if (!v){ a.x=0u; a.y=0u; a.z=0u; a.w=0u; }
      uint4 bf = wb[(t*8+ch)*64 + lane];
      acc = __builtin_amdgcn_mfma_f32_32x32x16_f16(*(half8*)&a, *(half8*)&bf, acc, 0, 0, 0);
    }
  }

  int o = lane & 31;
  #pragma unroll
  for (int r=0;r<16;r++){
    int pxl = w0 + ((r&3) + 8*(r>>2) + 4*half);
    if (o < NOFF) piv[pxl][o] = acc[r];
  }
  __syncthreads();

  if (tid < 128){
    int wpx = tid;
    float v[NOFF];
    #pragma unroll
    for (int oo=0;oo<NOFF;oo++) v[oo] = piv[wpx][oo] + b_off[oo];

    u32 rec[36];
    #pragma unroll
    for (int kk=0;kk<9;kk++){
      float py = (float)(h + kk/3 - 1) + v[2*kk];
      float qx = (float)(wpx + kk%3 - 1) + v[2*kk+1];
      float fy = floorf(py), fx = floorf(qx);
      float ty = py - fy, tx = qx - fx;
      int y0 = (int)fy, x0 = (int)fx;
      int y1 = y0+1, x1 = x0+1;
      bool vy0 = (y0>=0)&&(y0<Hh), vy1=(y1>=0)&&(y1<Hh);
      bool vx0 = (x0>=0)&&(x0<Ww), vx1=(x1>=0)&&(x1<Ww);
      u32 yc0 = (u32)(min(max(y0,0),Hh-1)*Ww), yc1 = (u32)(min(max(y1,0),Hh-1)*Ww);
      u32 xc0 = (u32)min(max(x0,0),Ww-1),      xc1 = (u32)min(max(x1,0),Ww-1);
      rec[2*kk]   = (yc0+xc0) | ((yc0+xc1)<<16);
      rec[2*kk+1] = (yc1+xc0) | ((yc1+xc1)<<16);
      float c00 = (vy0&&vx0) ? (1.f-ty)*(1.f-tx) : 0.f;
      float c01 = (vy0&&vx1) ? (1.f-ty)*tx       : 0.f;
      float c10 = (vy1&&vx0) ? ty*(1.f-tx)       : 0.f;
      float c11 = (vy1&&vx1) ? ty*tx             : 0.f;
      rec[18+2*kk] = pack2h(c00, c01);
      rec[19+2*kk] = pack2h(c10, c11);
    }
    int pxg = blockIdx.x*128 + wpx;
    uint4* dst = (uint4*)(recs + (size_t)pxg*36);
    #pragma unroll
    for (int q=0;q<9;q++) dst[q] = *(uint4*)(rec + q*4);
  }
}

// ---------------- K2: deformable depthwise (f16 gathers, fma_mix) + fused stats ----------------
template<bool F16OUT>
__global__ __launch_bounds__(256) void k_deform_rec(const u32* __restrict__ xt, const u32* __restrict__ recs,
                                                    const float* __restrict__ wdt, float* __restrict__ out,
                                                    u32* __restrict__ dwb, float* __restrict__ bps){
  __shared__ float pivot[16][132];
  int tid = threadIdx.x, lane = tid & 63, wid = tid >> 6;
  int pxb = blockIdx.x * 16;
  int bu = pxb >> 14, hw0 = pxb & 16383;
  int l2 = lane*2;

  float2 wk[9];
  #pragma unroll
  for (int k=0;k<9;k++) wk[k] = *(const float2*)(wdt + k*Cc + l2);

  const u32* xbu = xt + (size_t)bu*HW*64;

  #pragma unroll
  for (int i=0;i<4;i++){
    int pu = __builtin_amdgcn_readfirstlane(pxb + wid*4 + i);
    const u32* rec = recs + (size_t)pu*36;

    u32 q[9][4];
    #pragma unroll
    for (int kk=0;kk<9;kk++){
      u32 dA = rec[2*kk], dB = rec[2*kk+1];
      q[kk][0] = xbu[(size_t)(dA & 0xFFFFu)*64 + lane];
      q[kk][1] = xbu[(size_t)(dA >> 16)   *64 + lane];
      q[kk][2] = xbu[(size_t)(dB & 0xFFFFu)*64 + lane];
      q[kk][3] = xbu[(size_t)(dB >> 16)   *64 + lane];
    }

    float acc0 = 0.f, acc1 = 0.f;
    #pragma unroll
    for (int kk=0;kk<9;kk++){
      u32 uA = rec[18+2*kk], uB = rec[19+2*kk];
      __half2 hA = *(__half2*)&uA, hB = *(__half2*)&uB;
      __half2 q0 = *(__half2*)&q[kk][0], q1 = *(__half2*)&q[kk][1];
      __half2 q2 = *(__half2*)&q[kk][2], q3 = *(__half2*)&q[kk][3];
      // fma_mix pattern: (float)h * (float)h + f
      float s0 = 0.f, s1 = 0.f;
      s0 = fmaf(__low2float(hA),  __low2float(q0),  s0);
      s0 = fmaf(__high2float(hA), __low2float(q1),  s0);
      s0 = fmaf(__low2float(hB),  __low2float(q2),  s0);
      s0 = fmaf(__high2float(hB), __low2float(q3),  s0);
      s1 = fmaf(__low2float(hA),  __high2float(q0), s1);
      s1 = fmaf(__high2float(hA), __high2float(q1), s1);
      s1 = fmaf(__low2float(hB),  __high2float(q2), s1);
      s1 = fmaf(__high2float(hB), __high2float(q3), s1);
      acc0 = fmaf(wk[kk].x, s0, acc0);
      acc1 = fmaf(wk[kk].y, s1, acc1);
    }
    pivot[wid*4+i][l2]   = acc0;
    pivot[wid*4+i][l2+1] = acc1;
  }
  __syncthreads();
  #pragma unroll
  for (int it=0; it<2; it++){
    int c = (tid>>2) + it*64, qd = tid & 3;
    float4 r = make_float4(pivot[qd*4+0][c], pivot[qd*4+1][c], pivot[qd*4+2][c], pivot[qd*4+3][c]);
    float s  = (r.x + r.y) + (r.z + r.w);
    float s2 = fmaf(r.x,r.x, fmaf(r.y,r.y, fmaf(r.z,r.z, r.w*r.w)));
    s  += __shfl_down(s, 2, 4);  s  += __shfl_down(s, 1, 4);
    s2 += __shfl_down(s2, 2, 4); s2 += __shfl_down(s2, 1, 4);
    if (qd == 0){
      bps[(size_t)blockIdx.x*256 + c]       = s;
      bps[(size_t)blockIdx.x*256 + 128 + c] = s2;
    }
    if (F16OUT){
      uint2 pp; pp.x = pack2h(r.x, r.y); pp.y = pack2h(r.z, r.w);
      *(uint2*)&dwb[(((size_t)bu*Cc + c)*HW + hw0)/2 + qd*2] = pp;
    } else {
      *(float4*)(out + ((size_t)bu*Cc + c)*HW + hw0 + qd*4) = r;
    }
  }
}

// ---------------- stats reduce ----------------
__global__ __launch_bounds__(256) void k_statsr1(const float* __restrict__ bps, float* __restrict__ part2){
  int tid = threadIdx.x;
  size_t base = (size_t)blockIdx.x * 64;
  float a = 0.f;
  for (int r=0;r<64;r++) a += bps[(base + r)*256 + tid];
  part2[blockIdx.x*256 + tid] = a;
}

__global__ __launch_bounds__(256) void k_statsr2(const float* __restrict__ part2, float* __restrict__ mr){
  __shared__ float t[256];
  int tid = threadIdx.x;
  float a = 0.f;
  for (int r=0;r<128;r++) a += part2[r*256 + tid];
  t[tid] = a;
  __syncthreads();
  if (tid < 128){
    float S = t[tid], S2 = t[128 + tid];
    const float invN = 1.f/(float)(Bb*HW);
    float m = S*invN;
    float var = S2*invN - m*m;
    mr[tid]       = m;
    mr[Cc + tid]  = rsqrtf(var + 1e-5f);
  }
}

// ---------------- apply: BN + SiLU + residual ----------------
__global__ __launch_bounds__(256) void k_apply_f32(float* __restrict__ out, const float* __restrict__ x,
                                                   const float* __restrict__ mr, const float* __restrict__ gamma,
                                                   const float* __restrict__ beta){
  int i = blockIdx.x*256 + threadIdx.x;
  int c = (i >> 12) & 127;
  float4 v  = ((const float4*)out)[i];
  float4 xi = ((const float4*)x)[i];
  float m = mr[c], r = mr[Cc+c], g = gamma[c], be = beta[c];
  float* vp = (float*)&v; const float* xp = (const float*)&xi;
  float4 o; float* op = (float*)&o;
  #pragma unroll
  for (int j=0;j<4;j++){
    float t = (vp[j]-m)*r*g + be;
    t = t / (1.f + expf(-t));
    op[j] = t + xp[j];
  }
  ((float4*)out)[i] = o;
}

__global__ __launch_bounds__(256) void k_apply_f16(const u32* __restrict__ dwb, float* __restrict__ out,
                                                   const float* __restrict__ x, const float* __restrict__ mr,
                                                   const float* __restrict__ gamma, const float* __restrict__ beta){
  int i = blockIdx.x*256 + threadIdx.x;
  int c = (i >> 12) & 127;
  uint2 dw = ((const uint2*)dwb)[i];
  float4 xi = ((const float4*)x)[i];
  float m = mr[c], r = mr[Cc+c], g = gamma[c], be = beta[c];
  __half2 d0 = *(__half2*)&dw.x, d1 = *(__half2*)&dw.y;
  float v[4];
  v[0] = __low2float(d0); v[1] = __high2float(d0);
  v[2] = __low2float(d1); v[3] = __high2float(d1);
  const float* xp = (const float*)&xi;
  float4 o; float* op = (float*)&o;
  #pragma unroll
  for (int j=0;j<4;j++){
    float t = (v[j]-m)*r*g + be;
    t = t / (1.f + expf(-t));
    op[j] = t + xp[j];
  }
  ((float4*)out)[i] = o;
}

extern "C" void kernel_launch(void* const* d_in, const int* in_sizes, int n_in,
                              void* d_out, int out_size, void* d_ws, size_t ws_size,
                              hipStream_t stream) {
  const float* x     = (const float*)d_in[0];
  const float* w_off = (const float*)d_in[1];
  const float* b_off = (const float*)d_in[2];
  const float* w_dw  = (const float*)d_in[3];
  const float* gamma = (const float*)d_in[4];
  const float* beta  = (const float*)d_in[5];
  float* out = (float*)d_out;

  u32*   wBf  = (u32*)d_ws;                            // 18432
  float* wdt  = (float*)d_ws + 23040;                  // 1152
  float* mr   = (float*)d_ws + 24576;                  // 256
  u32*   recs = (u32*)d_ws + 32768;                    // NPIX*36
  u32*   xt16 = recs + (size_t)NPIX*36;                // NPIX*64
  float* bps  = (float*)(xt16 + (size_t)NPIX*64);      // 8192*256
  float* part2= bps + (size_t)8192*256;                // 128*256
  u32*   dwb  = (u32*)(part2 + 128*256);               // NPIX*64 (f16 out_dw), big path only

  const size_t NEED_B = ((size_t)32768 + (size_t)NPIX*36 + (size_t)NPIX*64
                         + (size_t)8192*256 + 128*256 + (size_t)NPIX*64) * 4;
  bool big = (ws_size >= NEED_B);

  hipLaunchKernelGGL(k_repack, dim3((72*64*4 + 9*Cc + 255)/256), dim3(256), 0, stream, w_off, w_dw, wBf, wdt);
  hipLaunchKernelGGL(k_tx,     dim3(2048), dim3(256), 0, stream, x, xt16);
  hipLaunchKernelGGL(k_offset_mfma, dim3(1024), dim3(256), 0, stream, xt16, wBf, b_off, recs);

  if (big){
    hipLaunchKernelGGL((k_deform_rec<true>), dim3(NPIX/16), dim3(256), 0, stream, xt16, recs, wdt, out, dwb, bps);
  } else {
    hipLaunchKernelGGL((k_deform_rec<false>), dim3(NPIX/16), dim3(256), 0, stream, xt16, recs, wdt, out, dwb, bps);
  }
  hipLaunchKernelGGL(k_statsr1, dim3(128), dim3(256), 0, stream, bps, part2);
  hipLaunchKernelGGL(k_statsr2, dim3(1),   dim3(256), 0, stream, part2, mr);
  if (big){
    hipLaunchKernelGGL(k_apply_f16, dim3(NPIX*Cc/4/256), dim3(256), 0, stream, dwb, out, x, mr, gamma, beta);
  } else {
    hipLaunchKernelGGL(k_apply_f32, dim3(NPIX*Cc/4/256), dim3(256), 0, stream, out, x, mr, gamma, beta);
  }
}

// Round 12
// 158.058 us; speedup vs baseline: 5.9061x; 1.0739x over previous
//
#include <hip/hip_runtime.h>
#include <hip/hip_fp16.h>
#include <math.h>

#define Cc 128
#define Hh 128
#define Ww 128
#define Bb 8
#define HW 16384
#define NPIX 131072   // B*H*W
#define NOFF 18

typedef unsigned int u32;
typedef _Float16 half8 __attribute__((ext_vector_type(8)));
typedef __attribute__((ext_vector_type(16))) float f32x16;

static __device__ __forceinline__ u32 pack2h(float a, float b){
  __half2 h = __floats2half2_rn(a, b);
  return *(u32*)&h;
}

// ---------------- K0: pack B-fragments (f16) + w_dw packed half2 [k][cpair] ----------------
__global__ __launch_bounds__(256) void k_repack(const float* __restrict__ w_off, const float* __restrict__ w_dw,
                                                u32* __restrict__ wBf, u32* __restrict__ wdt_h){
  int i = blockIdx.x*256 + threadIdx.x;
  if (i < 72*64*4){
    int step = i >> 8;
    int r    = i & 255;
    int lane = r >> 2;
    int q    = r & 3;
    int tap  = step / 8, chunk = step % 8;
    int o    = lane & 31, half = lane >> 5;
    int c0   = chunk*16 + half*8 + 2*q;
    float v0 = (o < NOFF) ? w_off[(size_t)(o*Cc + c0    )*9 + tap] : 0.f;
    float v1 = (o < NOFF) ? w_off[(size_t)(o*Cc + c0 + 1)*9 + tap] : 0.f;
    wBf[i] = pack2h(v0, v1);
  }
  int j = i - 72*64*4;
  if (j >= 0 && j < 9*64){
    int cp = j & 63; int k = j >> 6;
    wdt_h[j] = pack2h(w_dw[(2*cp)*9 + k], w_dw[(2*cp+1)*9 + k]);
  }
}

// ---------------- K_tx: transpose x NCHW -> NHWC, f16-packed (2 ch per u32) ----------------
__global__ __launch_bounds__(256) void k_tx(const float* __restrict__ x, u32* __restrict__ xt16){
  __shared__ float t[128][65];
  int tid = threadIdx.x;
  int b   = blockIdx.x >> 8;
  int hw0 = (blockIdx.x & 255) << 6;
  int lane = tid & 63, wg = tid >> 6;
  const float* xb = x + (size_t)b*Cc*HW;
  #pragma unroll
  for (int k=0;k<32;k++){
    int c = wg + k*4;
    t[c][lane] = xb[(size_t)c*HW + hw0 + lane];
  }
  __syncthreads();
  u32* ob = xt16 + ((size_t)b*HW + hw0)*64;
  int cpair = tid & 63, grp = tid >> 6;
  #pragma unroll
  for (int k=0;k<16;k++){
    int hwl = grp + k*4;
    ob[(size_t)hwl*64 + cpair] = pack2h(t[cpair*2][hwl], t[cpair*2+1][hwl]);
  }
}

// ---------------- K1: offset conv via f16 MFMA + fused record build ----------------
__global__ __launch_bounds__(256) void k_offset_mfma(const u32* __restrict__ xt, const u32* __restrict__ wBf,
                                                     const float* __restrict__ b_off, u32* __restrict__ recs){
  __shared__ float piv[128][21];
  int tid = threadIdx.x, lane = tid & 63, wid = tid >> 6;
  int b = blockIdx.x >> 7, h = blockIdx.x & 127;
  int row = lane & 31, half = lane >> 5;
  int w0 = wid*32;
  int w = w0 + row;

  const u32* xb = xt + (size_t)b*HW*64;

  int taddr[9]; bool tval[9];
  #pragma unroll
  for (int t=0;t<9;t++){
    int ky = t/3 - 1, kx = t%3 - 1;
    int hh = h + ky, wt = w + kx;
    bool v = (hh>=0)&&(hh<Hh)&&(wt>=0)&&(wt<Ww);
    int hwd = hh*Ww + wt;
    hwd = min(max(hwd,0),HW-1);
    taddr[t] = hwd*64 + half*4;
    tval[t] = v;
  }

  f32x16 acc;
  #pragma unroll
  for (int i=0;i<16;i++) acc[i] = 0.f;

  const uint4* wb = (const uint4*)wBf;
  #pragma unroll 1
  for (int t=0;t<9;t++){
    const uint4* ap = (const uint4*)(xb + taddr[t]);
    bool v = tval[t];
    #pragma unroll
    for (int ch=0;ch<8;ch++){
      uint4 a = ap[ch*2];
      if (!v){ a.x=0u; a.y=0u; a.z=0u; a.w=0u; }
      uint4 bf = wb[(t*8+ch)*64 + lane];
      acc = __builtin_amdgcn_mfma_f32_32x32x16_f16(*(half8*)&a, *(half8*)&bf, acc, 0, 0, 0);
    }
  }

  int o = lane & 31;
  #pragma unroll
  for (int r=0;r<16;r++){
    int pxl = w0 + ((r&3) + 8*(r>>2) + 4*half);
    if (o < NOFF) piv[pxl][o] = acc[r];
  }
  __syncthreads();

  if (tid < 128){
    int wpx = tid;
    float v[NOFF];
    #pragma unroll
    for (int oo=0;oo<NOFF;oo++) v[oo] = piv[wpx][oo] + b_off[oo];

    u32 rec[36];
    #pragma unroll
    for (int kk=0;kk<9;kk++){
      float py = (float)(h + kk/3 - 1) + v[2*kk];
      float qx = (float)(wpx + kk%3 - 1) + v[2*kk+1];
      float fy = floorf(py), fx = floorf(qx);
      float ty = py - fy, tx = qx - fx;
      int y0 = (int)fy, x0 = (int)fx;
      int y1 = y0+1, x1 = x0+1;
      bool vy0 = (y0>=0)&&(y0<Hh), vy1=(y1>=0)&&(y1<Hh);
      bool vx0 = (x0>=0)&&(x0<Ww), vx1=(x1>=0)&&(x1<Ww);
      u32 yc0 = (u32)(min(max(y0,0),Hh-1)*Ww), yc1 = (u32)(min(max(y1,0),Hh-1)*Ww);
      u32 xc0 = (u32)min(max(x0,0),Ww-1),      xc1 = (u32)min(max(x1,0),Ww-1);
      rec[2*kk]   = (yc0+xc0) | ((yc0+xc1)<<16);
      rec[2*kk+1] = (yc1+xc0) | ((yc1+xc1)<<16);
      float c00 = (vy0&&vx0) ? (1.f-ty)*(1.f-tx) : 0.f;
      float c01 = (vy0&&vx1) ? (1.f-ty)*tx       : 0.f;
      float c10 = (vy1&&vx0) ? ty*(1.f-tx)       : 0.f;
      float c11 = (vy1&&vx1) ? ty*tx             : 0.f;
      rec[18+2*kk] = pack2h(c00, c01);
      rec[19+2*kk] = pack2h(c10, c11);
    }
    int pxg = blockIdx.x*128 + wpx;
    uint4* dst = (uint4*)(recs + (size_t)pxg*36);
    #pragma unroll
    for (int q=0;q<9;q++) dst[q] = *(uint4*)(rec + q*4);
  }
}

// ---------------- K2: deformable depthwise — packed-f16 bilinear, fused stats ----------------
template<bool F16OUT>
__global__ __launch_bounds__(256) void k_deform_rec(const u32* __restrict__ xt, const u32* __restrict__ recs,
                                                    const u32* __restrict__ wdt_h, float* __restrict__ out,
                                                    u32* __restrict__ dwb, float* __restrict__ bps){
  __shared__ float pivot[16][132];
  int tid = threadIdx.x, lane = tid & 63, wid = tid >> 6;
  int pxb = blockIdx.x * 16;
  int bu = pxb >> 14, hw0 = pxb & 16383;
  int l2 = lane*2;

  __half2 wk2[9];
  #pragma unroll
  for (int k=0;k<9;k++){
    u32 wv = wdt_h[k*64 + lane];
    wk2[k] = *(__half2*)&wv;
  }

  const u32* xbu = xt + (size_t)bu*HW*64;

  #pragma unroll
  for (int i=0;i<4;i++){
    int pu = __builtin_amdgcn_readfirstlane(pxb + wid*4 + i);
    const u32* rec = recs + (size_t)pu*36;

    u32 q[9][4];
    #pragma unroll
    for (int kk=0;kk<9;kk++){
      u32 dA = rec[2*kk], dB = rec[2*kk+1];
      q[kk][0] = xbu[(size_t)(dA & 0xFFFFu)*64 + lane];
      q[kk][1] = xbu[(size_t)(dA >> 16)   *64 + lane];
      q[kk][2] = xbu[(size_t)(dB & 0xFFFFu)*64 + lane];
      q[kk][3] = xbu[(size_t)(dB >> 16)   *64 + lane];
    }

    __half2 acc2 = __floats2half2_rn(0.f, 0.f);
    #pragma unroll
    for (int kk=0;kk<9;kk++){
      u32 uA = rec[18+2*kk], uB = rec[19+2*kk];
      __half2 hA = *(__half2*)&uA, hB = *(__half2*)&uB;
      __half2 q0 = *(__half2*)&q[kk][0], q1 = *(__half2*)&q[kk][1];
      __half2 q2 = *(__half2*)&q[kk][2], q3 = *(__half2*)&q[kk][3];
      __half2 s = __hmul2(__low2half2(hA), q0);
      s = __hfma2(__high2half2(hA), q1, s);
      s = __hfma2(__low2half2(hB),  q2, s);
      s = __hfma2(__high2half2(hB), q3, s);
      acc2 = __hfma2(wk2[kk], s, acc2);
    }
    pivot[wid*4+i][l2]   = __low2float(acc2);
    pivot[wid*4+i][l2+1] = __high2float(acc2);
  }
  __syncthreads();
  #pragma unroll
  for (int it=0; it<2; it++){
    int c = (tid>>2) + it*64, qd = tid & 3;
    float4 r = make_float4(pivot[qd*4+0][c], pivot[qd*4+1][c], pivot[qd*4+2][c], pivot[qd*4+3][c]);
    float s  = (r.x + r.y) + (r.z + r.w);
    float s2 = fmaf(r.x,r.x, fmaf(r.y,r.y, fmaf(r.z,r.z, r.w*r.w)));
    s  += __shfl_down(s, 2, 4);  s  += __shfl_down(s, 1, 4);
    s2 += __shfl_down(s2, 2, 4); s2 += __shfl_down(s2, 1, 4);
    if (qd == 0){
      bps[(size_t)blockIdx.x*256 + c]       = s;
      bps[(size_t)blockIdx.x*256 + 128 + c] = s2;
    }
    if (F16OUT){
      uint2 pp; pp.x = pack2h(r.x, r.y); pp.y = pack2h(r.z, r.w);
      *(uint2*)&dwb[(((size_t)bu*Cc + c)*HW + hw0)/2 + qd*2] = pp;
    } else {
      *(float4*)(out + ((size_t)bu*Cc + c)*HW + hw0 + qd*4) = r;
    }
  }
}

// ---------------- stats reduce ----------------
__global__ __launch_bounds__(256) void k_statsr1(const float* __restrict__ bps, float* __restrict__ part2){
  int tid = threadIdx.x;
  size_t base = (size_t)blockIdx.x * 64;
  float a = 0.f;
  for (int r=0;r<64;r++) a += bps[(base + r)*256 + tid];
  part2[blockIdx.x*256 + tid] = a;
}

__global__ __launch_bounds__(256) void k_statsr2(const float* __restrict__ part2, float* __restrict__ mr){
  __shared__ float t[256];
  int tid = threadIdx.x;
  float a = 0.f;
  for (int r=0;r<128;r++) a += part2[r*256 + tid];
  t[tid] = a;
  __syncthreads();
  if (tid < 128){
    float S = t[tid], S2 = t[128 + tid];
    const float invN = 1.f/(float)(Bb*HW);
    float m = S*invN;
    float var = S2*invN - m*m;
    mr[tid]       = m;
    mr[Cc + tid]  = rsqrtf(var + 1e-5f);
  }
}

// ---------------- apply: BN + SiLU + residual ----------------
__global__ __launch_bounds__(256) void k_apply_f32(float* __restrict__ out, const float* __restrict__ x,
                                                   const float* __restrict__ mr, const float* __restrict__ gamma,
                                                   const float* __restrict__ beta){
  int i = blockIdx.x*256 + threadIdx.x;
  int c = (i >> 12) & 127;
  float4 v  = ((const float4*)out)[i];
  float4 xi = ((const float4*)x)[i];
  float m = mr[c], r = mr[Cc+c], g = gamma[c], be = beta[c];
  float* vp = (float*)&v; const float* xp = (const float*)&xi;
  float4 o; float* op = (float*)&o;
  #pragma unroll
  for (int j=0;j<4;j++){
    float t = (vp[j]-m)*r*g + be;
    t = t / (1.f + expf(-t));
    op[j] = t + xp[j];
  }
  ((float4*)out)[i] = o;
}

__global__ __launch_bounds__(256) void k_apply_f16(const u32* __restrict__ dwb, float* __restrict__ out,
                                                   const float* __restrict__ x, const float* __restrict__ mr,
                                                   const float* __restrict__ gamma, const float* __restrict__ beta){
  int i = blockIdx.x*256 + threadIdx.x;
  int c = (i >> 12) & 127;
  uint2 dw = ((const uint2*)dwb)[i];
  float4 xi = ((const float4*)x)[i];
  float m = mr[c], r = mr[Cc+c], g = gamma[c], be = beta[c];
  __half2 d0 = *(__half2*)&dw.x, d1 = *(__half2*)&dw.y;
  float v[4];
  v[0] = __low2float(d0); v[1] = __high2float(d0);
  v[2] = __low2float(d1); v[3] = __high2float(d1);
  const float* xp = (const float*)&xi;
  float4 o; float* op = (float*)&o;
  #pragma unroll
  for (int j=0;j<4;j++){
    float t = (v[j]-m)*r*g + be;
    t = t / (1.f + expf(-t));
    op[j] = t + xp[j];
  }
  ((float4*)out)[i] = o;
}

extern "C" void kernel_launch(void* const* d_in, const int* in_sizes, int n_in,
                              void* d_out, int out_size, void* d_ws, size_t ws_size,
                              hipStream_t stream) {
  const float* x     = (const float*)d_in[0];
  const float* w_off = (const float*)d_in[1];
  const float* b_off = (const float*)d_in[2];
  const float* w_dw  = (const float*)d_in[3];
  const float* gamma = (const float*)d_in[4];
  const float* beta  = (const float*)d_in[5];
  float* out = (float*)d_out;

  u32*   wBf  = (u32*)d_ws;                            // 18432
  u32*   wdt_h= (u32*)d_ws + 23040;                    // 576
  float* mr   = (float*)d_ws + 24576;                  // 256
  u32*   recs = (u32*)d_ws + 32768;                    // NPIX*36
  u32*   xt16 = recs + (size_t)NPIX*36;                // NPIX*64
  float* bps  = (float*)(xt16 + (size_t)NPIX*64);      // 8192*256
  float* part2= bps + (size_t)8192*256;                // 128*256
  u32*   dwb  = (u32*)(part2 + 128*256);               // NPIX*64 (f16 out_dw), big path only

  const size_t NEED_B = ((size_t)32768 + (size_t)NPIX*36 + (size_t)NPIX*64
                         + (size_t)8192*256 + 128*256 + (size_t)NPIX*64) * 4;
  bool big = (ws_size >= NEED_B);

  hipLaunchKernelGGL(k_repack, dim3((72*64*4 + 9*64 + 255)/256), dim3(256), 0, stream, w_off, w_dw, wBf, wdt_h);
  hipLaunchKernelGGL(k_tx,     dim3(2048), dim3(256), 0, stream, x, xt16);
  hipLaunchKernelGGL(k_offset_mfma, dim3(1024), dim3(256), 0, stream, xt16, wBf, b_off, recs);

  if (big){
    hipLaunchKernelGGL((k_deform_rec<true>), dim3(NPIX/16), dim3(256), 0, stream, xt16, recs, wdt_h, out, dwb, bps);
  } else {
    hipLaunchKernelGGL((k_deform_rec<false>), dim3(NPIX/16), dim3(256), 0, stream, xt16, recs, wdt_h, out, dwb, bps);
  }
  hipLaunchKernelGGL(k_statsr1, dim3(128), dim3(256), 0, stream, bps, part2);
  hipLaunchKernelGGL(k_statsr2, dim3(1),   dim3(256), 0, stream, part2, mr);
  if (big){
    hipLaunchKernelGGL(k_apply_f16, dim3(NPIX*Cc/4/256), dim3(256), 0, stream, dwb, out, x, mr, gamma, beta);
  } else {
    hipLaunchKernelGGL(k_apply_f32, dim3(NPIX*Cc/4/256), dim3(256), 0, stream, out, x, mr, gamma, beta);
  }
}